// Round 2
// baseline (902.962 us; speedup 1.0000x reference)
//
#include <hip/hip_runtime.h>

typedef short short8 __attribute__((ext_vector_type(8)));
typedef float f32x4 __attribute__((ext_vector_type(4)));

#define LDK 40   // padded LDS K-stride for GEMM tiles (80B rows: 16B-aligned)
#define SEQ 2048

__device__ __forceinline__ unsigned short f2bf(float f) {
    unsigned int u = __builtin_bit_cast(unsigned int, f);
    unsigned int r = (u + 0x7fffu + ((u >> 16) & 1u)) >> 16;
    return (unsigned short)r;
}

// ---------------------------------------------------------------------------
// Weight transpose + fp32->bf16 convert:  Wt[n*K + k] = bf16(W[k*N + n])
// ---------------------------------------------------------------------------
__global__ __launch_bounds__(256)
void wtrans_kernel(const float* __restrict__ W, unsigned short* __restrict__ Wt,
                   int Kd, int Nd)
{
    __shared__ float t[32][33];
    const int tx = threadIdx.x & 31;
    const int ty = threadIdx.x >> 5;   // 0..7
    const int nb = blockIdx.x * 32;
    const int kb = blockIdx.y * 32;
#pragma unroll
    for (int i = 0; i < 4; i++)
        t[ty + i * 8][tx] = W[(size_t)(kb + ty + i * 8) * Nd + nb + tx];
    __syncthreads();
#pragma unroll
    for (int i = 0; i < 4; i++)
        Wt[(size_t)(nb + ty + i * 8) * Kd + kb + tx] = f2bf(t[tx][ty + i * 8]);
}

// ---------------------------------------------------------------------------
// Elementwise fp32 -> bf16
// ---------------------------------------------------------------------------
__global__ __launch_bounds__(256)
void cvt_kernel(const float* __restrict__ in, unsigned short* __restrict__ out, int n)
{
    int i = (blockIdx.x * 256 + threadIdx.x) * 4;
    if (i < n) {
        float4 v = *(const float4*)(in + i);
        ushort4 o;
        o.x = f2bf(v.x); o.y = f2bf(v.y); o.z = f2bf(v.z); o.w = f2bf(v.w);
        *(ushort4*)(out + i) = o;
    }
}

// ---------------------------------------------------------------------------
// LayerNorm (torch-faithful: ddof=1, eps added to std). fp32 in -> bf16 out.
// One 256-thread block per row, D=1024.
// ---------------------------------------------------------------------------
__global__ __launch_bounds__(256)
void ln_kernel(const float* __restrict__ x, const float* __restrict__ g,
               const float* __restrict__ bb, unsigned short* __restrict__ out)
{
    const int D = 1024;
    const int row = blockIdx.x;
    const float* xr = x + (size_t)row * D;
    float v[4];
    float s = 0.f, ss = 0.f;
#pragma unroll
    for (int i = 0; i < 4; i++) {
        v[i] = xr[threadIdx.x + i * 256];
        s += v[i];
        ss += v[i] * v[i];
    }
#pragma unroll
    for (int off = 1; off < 64; off <<= 1) {
        s  += __shfl_xor(s,  off, 64);
        ss += __shfl_xor(ss, off, 64);
    }
    __shared__ float red[8];
    const int wave = threadIdx.x >> 6;
    if ((threadIdx.x & 63) == 0) { red[wave] = s; red[4 + wave] = ss; }
    __syncthreads();
    s  = red[0] + red[1] + red[2] + red[3];
    ss = red[4] + red[5] + red[6] + red[7];
    float mean = s / D;
    float var  = fmaxf((ss - s * mean) / (D - 1), 0.f);
    float inv  = 1.f / (sqrtf(var) + 1e-6f);
#pragma unroll
    for (int i = 0; i < 4; i++) {
        int c = threadIdx.x + i * 256;
        out[(size_t)row * D + c] = f2bf(g[c] * (v[i] - mean) * inv + bb[c]);
    }
}

// ---------------------------------------------------------------------------
// Tiled MFMA GEMM: C[M,N] = A[M,K] @ Wt[N,K]^T + bias
// A bf16 row-major, Wt bf16 row-major [N][K] (pre-transposed weight).
// 128x128 block tile, BK=32, 4 waves each computing 64x64 (4x4 subtiles).
// Each thread stages 16 elements (2 x short8) of As and Bs per K-step.
// MODE 1: bf16 out scattered to [B,H,S,64] head layout (QKV projections)
// MODE 2: relu -> bf16 out row-major [M,N]                (FFN first GEMM)
// MODE 3: + res (fp32) -> fp32 out row-major [M,N]        (output projections)
// ---------------------------------------------------------------------------
template <int MODE>
__global__ __launch_bounds__(256)
void gemm_kernel(const unsigned short* __restrict__ A,
                 const unsigned short* __restrict__ Wt,
                 const float* __restrict__ bias,
                 const float* __restrict__ res,
                 float* __restrict__ outf,
                 unsigned short* __restrict__ outb,
                 int M, int N, int K)
{
    __shared__ unsigned short As[128 * LDK];
    __shared__ unsigned short Bs[128 * LDK];
    const int tid  = threadIdx.x;
    const int lane = tid & 63;
    const int wave = tid >> 6;
    const int quad = lane >> 4;
    const int l16  = lane & 15;
    const int m0 = blockIdx.y * 128;
    const int n0 = blockIdx.x * 128;
    const int wm = (wave >> 1) << 6;  // 0 or 64
    const int wn = (wave & 1) << 6;   // 0 or 64
    const int srow = tid >> 1;        // 0..127
    const int scol = (tid & 1) << 4;  // 0 or 16 (each thread covers scol..scol+15)

    f32x4 acc[4][4];
#pragma unroll
    for (int i = 0; i < 4; i++)
#pragma unroll
        for (int j = 0; j < 4; j++) acc[i][j] = f32x4{0.f, 0.f, 0.f, 0.f};

    const unsigned short* Ag = A  + (size_t)(m0 + srow) * K + scol;
    const unsigned short* Bg = Wt + (size_t)(n0 + srow) * K + scol;
    unsigned short* Asw = &As[srow * LDK + scol];
    unsigned short* Bsw = &Bs[srow * LDK + scol];

    for (int k0 = 0; k0 < K; k0 += 32) {
        short8 a0 = *(const short8*)(Ag + k0);
        short8 a1 = *(const short8*)(Ag + k0 + 8);
        short8 b0 = *(const short8*)(Bg + k0);
        short8 b1 = *(const short8*)(Bg + k0 + 8);
        *(short8*)(Asw)     = a0;
        *(short8*)(Asw + 8) = a1;
        *(short8*)(Bsw)     = b0;
        *(short8*)(Bsw + 8) = b1;
        __syncthreads();
        short8 af[4], bfr[4];
#pragma unroll
        for (int i = 0; i < 4; i++)
            af[i] = *(const short8*)(&As[(wm + i * 16 + l16) * LDK + quad * 8]);
#pragma unroll
        for (int i = 0; i < 4; i++)
            bfr[i] = *(const short8*)(&Bs[(wn + i * 16 + l16) * LDK + quad * 8]);
#pragma unroll
        for (int mi = 0; mi < 4; mi++)
#pragma unroll
            for (int ni = 0; ni < 4; ni++)
                acc[mi][ni] = __builtin_amdgcn_mfma_f32_16x16x32_bf16(
                    af[mi], bfr[ni], acc[mi][ni], 0, 0, 0);
        __syncthreads();
    }

#pragma unroll
    for (int mi = 0; mi < 4; mi++) {
#pragma unroll
        for (int ni = 0; ni < 4; ni++) {
            const int colg = n0 + wn + ni * 16 + l16;
            const float bv = bias[colg];
#pragma unroll
            for (int r = 0; r < 4; r++) {
                const int rowg = m0 + wm + mi * 16 + quad * 4 + r;
                float v = acc[mi][ni][r] + bv;
                if (MODE == 1) {
                    int b = rowg >> 11, s = rowg & 2047;
                    int h = colg >> 6, d = colg & 63;
                    outb[((size_t)(b * 16 + h) * SEQ + s) * 64 + d] = f2bf(v);
                } else if (MODE == 2) {
                    outb[(size_t)rowg * N + colg] = f2bf(fmaxf(v, 0.f));
                } else {
                    outf[(size_t)rowg * N + colg] = v + res[(size_t)rowg * N + colg];
                }
            }
        }
    }
}

// ---------------------------------------------------------------------------
// Flash attention. Q,K,V bf16 [B,H,S,64]. O bf16 [B,S,1024] (concat heads).
// Block = 256 threads (4 waves); block handles 64 query rows of one (b,h);
// wave w owns rows [w*16, w*16+16). Key loop in 64-wide tiles, online softmax.
// ---------------------------------------------------------------------------
template <bool CAUSAL>
__global__ __launch_bounds__(256)
void attn_kernel(const unsigned short* __restrict__ Q,
                 const unsigned short* __restrict__ K,
                 const unsigned short* __restrict__ V,
                 unsigned short* __restrict__ O)
{
    __shared__ unsigned short Ks[64 * 72];   // [key][dk], stride 72
    __shared__ unsigned short Vt[64 * 72];   // [dk][key], stride 72
    __shared__ unsigned short Ps[4][16 * 72];// per-wave P tile [q][key]
    const int tid  = threadIdx.x;
    const int lane = tid & 63;
    const int wave = tid >> 6;
    const int quad = lane >> 4;
    const int l16  = lane & 15;
    const int bh = blockIdx.y;   // b*16 + h
    const int qb = blockIdx.x;
    const int q0 = qb * 64;
    const size_t base = (size_t)bh * SEQ * 64;

    short8 aq[2];
    {
        const unsigned short* qp = Q + base + (size_t)(q0 + wave * 16 + l16) * 64 + quad * 8;
        aq[0] = *(const short8*)(qp);
        aq[1] = *(const short8*)(qp + 32);
    }
    f32x4 acco[4];
#pragma unroll
    for (int i = 0; i < 4; i++) acco[i] = f32x4{0.f, 0.f, 0.f, 0.f};
    float m_i[4], l_i[4];
#pragma unroll
    for (int r = 0; r < 4; r++) { m_i[r] = -3.0e38f; l_i[r] = 0.f; }

    const int nkb = CAUSAL ? (qb + 1) : (SEQ / 64);
    const int srow = tid >> 2;         // 0..63
    const int c0   = (tid & 3) << 4;   // 0,16,32,48

    for (int kb = 0; kb < nkb; kb++) {
        const int k0 = kb * 64;
        __syncthreads();  // previous iteration's LDS reads complete
        {
            const unsigned short* kp = K + base + (size_t)(k0 + srow) * 64 + c0;
            *(short8*)(&Ks[srow * 72 + c0])     = *(const short8*)(kp);
            *(short8*)(&Ks[srow * 72 + c0 + 8]) = *(const short8*)(kp + 8);
            const unsigned short* vp = V + base + (size_t)(k0 + srow) * 64 + c0;
            short8 v0 = *(const short8*)(vp);
            short8 v1 = *(const short8*)(vp + 8);
#pragma unroll
            for (int j = 0; j < 8; j++) {
                Vt[(c0 + j) * 72 + srow]     = (unsigned short)v0[j];
                Vt[(c0 + 8 + j) * 72 + srow] = (unsigned short)v1[j];
            }
        }
        __syncthreads();

        // scores: S = Q K^T  (16q x 64keys per wave), C-layout
        f32x4 scf[4];
#pragma unroll
        for (int nt = 0; nt < 4; nt++) {
            f32x4 z = f32x4{0.f, 0.f, 0.f, 0.f};
#pragma unroll
            for (int c = 0; c < 2; c++) {
                short8 bk = *(const short8*)(&Ks[(nt * 16 + l16) * 72 + c * 32 + quad * 8]);
                z = __builtin_amdgcn_mfma_f32_16x16x32_bf16(aq[c], bk, z, 0, 0, 0);
            }
            scf[nt] = z;
        }
        // scale + mask
        float sv[4][4];
#pragma unroll
        for (int nt = 0; nt < 4; nt++)
#pragma unroll
            for (int r = 0; r < 4; r++) {
                float s = scf[nt][r] * 0.125f;
                if (CAUSAL) {
                    int qg = q0 + wave * 16 + quad * 4 + r;
                    int kg = k0 + nt * 16 + l16;
                    if (kg > qg) s = -1e9f;
                }
                sv[nt][r] = s;
            }
        // online softmax update (rows quad*4+r, distributed over 16 lanes)
#pragma unroll
        for (int r = 0; r < 4; r++) {
            float mx = fmaxf(fmaxf(sv[0][r], sv[1][r]), fmaxf(sv[2][r], sv[3][r]));
#pragma unroll
            for (int off = 1; off < 16; off <<= 1) mx = fmaxf(mx, __shfl_xor(mx, off, 64));
            float mnew  = fmaxf(m_i[r], mx);
            float alpha = __expf(m_i[r] - mnew);
            m_i[r] = mnew;
            float rs = 0.f;
#pragma unroll
            for (int nt = 0; nt < 4; nt++) {
                float pv = __expf(sv[nt][r] - mnew);
                sv[nt][r] = pv;
                rs += pv;
            }
#pragma unroll
            for (int off = 1; off < 16; off <<= 1) rs += __shfl_xor(rs, off, 64);
            l_i[r] = l_i[r] * alpha + rs;
#pragma unroll
            for (int nt = 0; nt < 4; nt++) acco[nt][r] *= alpha;
        }
        // P to LDS (C-layout -> memory), then read back in A-layout
#pragma unroll
        for (int nt = 0; nt < 4; nt++)
#pragma unroll
            for (int r = 0; r < 4; r++)
                Ps[wave][(quad * 4 + r) * 72 + nt * 16 + l16] = f2bf(sv[nt][r]);
        __syncthreads();
        // O += P @ V
#pragma unroll
        for (int c = 0; c < 2; c++) {
            short8 ap = *(const short8*)(&Ps[wave][l16 * 72 + c * 32 + quad * 8]);
#pragma unroll
            for (int nt = 0; nt < 4; nt++) {
                short8 bv = *(const short8*)(&Vt[(nt * 16 + l16) * 72 + c * 32 + quad * 8]);
                acco[nt] = __builtin_amdgcn_mfma_f32_16x16x32_bf16(ap, bv, acco[nt], 0, 0, 0);
            }
        }
    }
    // epilogue: O = acc / l, write to [B,S,1024]
    const int b = bh >> 4, h = bh & 15;
#pragma unroll
    for (int nt = 0; nt < 4; nt++)
#pragma unroll
        for (int r = 0; r < 4; r++) {
            int qg = q0 + wave * 16 + quad * 4 + r;
            float o = acco[nt][r] / l_i[r];
            O[((size_t)(b * SEQ + qg)) * 1024 + h * 64 + nt * 16 + l16] = f2bf(o);
        }
}

// ---------------------------------------------------------------------------
extern "C" void kernel_launch(void* const* d_in, const int* in_sizes, int n_in,
                              void* d_out, int out_size, void* d_ws, size_t ws_size,
                              hipStream_t stream)
{
    (void)in_sizes; (void)n_in; (void)out_size; (void)ws_size;
    const int B = 2, S = SEQ, D = 1024, DFF = 4096;
    const int M = B * S;  // 4096

    const float* x     = (const float*)d_in[0];
    const float* enc   = (const float*)d_in[1];
    const float* sa_wq = (const float*)d_in[4],  *sa_bq = (const float*)d_in[5];
    const float* sa_wk = (const float*)d_in[6],  *sa_bk = (const float*)d_in[7];
    const float* sa_wv = (const float*)d_in[8],  *sa_bv = (const float*)d_in[9];
    const float* sa_wo = (const float*)d_in[10], *sa_bo = (const float*)d_in[11];
    const float* ca_wq = (const float*)d_in[12], *ca_bq = (const float*)d_in[13];
    const float* ca_wk = (const float*)d_in[14], *ca_bk = (const float*)d_in[15];
    const float* ca_wv = (const float*)d_in[16], *ca_bv = (const float*)d_in[17];
    const float* ca_wo = (const float*)d_in[18], *ca_bo = (const float*)d_in[19];
    const float* ff_w1 = (const float*)d_in[20], *ff_b1 = (const float*)d_in[21];
    const float* ff_w2 = (const float*)d_in[22], *ff_b2 = (const float*)d_in[23];
    const float* n1_g  = (const float*)d_in[24], *n1_b = (const float*)d_in[25];
    const float* n2_g  = (const float*)d_in[26], *n2_b = (const float*)d_in[27];
    const float* n3_g  = (const float*)d_in[28], *n3_b = (const float*)d_in[29];
    float* out = (float*)d_out;

    char* p = (char*)d_ws;
    auto carve = [&](size_t bytes) -> char* {
        char* r = p;
        p += (bytes + 255) & ~(size_t)255;
        return r;
    };
    unsigned short* wt_saq = (unsigned short*)carve((size_t)D * D * 2);
    unsigned short* wt_sak = (unsigned short*)carve((size_t)D * D * 2);
    unsigned short* wt_sav = (unsigned short*)carve((size_t)D * D * 2);
    unsigned short* wt_sao = (unsigned short*)carve((size_t)D * D * 2);
    unsigned short* wt_caq = (unsigned short*)carve((size_t)D * D * 2);
    unsigned short* wt_cak = (unsigned short*)carve((size_t)D * D * 2);
    unsigned short* wt_cav = (unsigned short*)carve((size_t)D * D * 2);
    unsigned short* wt_cao = (unsigned short*)carve((size_t)D * D * 2);
    unsigned short* wt_ff1 = (unsigned short*)carve((size_t)D * DFF * 2);
    unsigned short* wt_ff2 = (unsigned short*)carve((size_t)DFF * D * 2);
    unsigned short* encb   = (unsigned short*)carve((size_t)M * D * 2);
    unsigned short* hb     = (unsigned short*)carve((size_t)M * D * 2);
    unsigned short* qbuf   = (unsigned short*)carve((size_t)M * D * 2);
    unsigned short* kbuf   = (unsigned short*)carve((size_t)M * D * 2);
    unsigned short* vbuf   = (unsigned short*)carve((size_t)M * D * 2);
    unsigned short* ffh    = (unsigned short*)carve((size_t)M * DFF * 2);
    float* x1 = (float*)carve((size_t)M * D * 4);
    unsigned short* abuf = hb;   // lifetimes disjoint: attn writes after hb's last read
    float* x2 = out;             // block-2 residual lands in d_out; block-3 reads+overwrites in place

    dim3 blk(256);
    // weight pre-pass: transpose + bf16 convert
    wtrans_kernel<<<dim3(D / 32, D / 32), blk, 0, stream>>>(sa_wq, wt_saq, D, D);
    wtrans_kernel<<<dim3(D / 32, D / 32), blk, 0, stream>>>(sa_wk, wt_sak, D, D);
    wtrans_kernel<<<dim3(D / 32, D / 32), blk, 0, stream>>>(sa_wv, wt_sav, D, D);
    wtrans_kernel<<<dim3(D / 32, D / 32), blk, 0, stream>>>(sa_wo, wt_sao, D, D);
    wtrans_kernel<<<dim3(D / 32, D / 32), blk, 0, stream>>>(ca_wq, wt_caq, D, D);
    wtrans_kernel<<<dim3(D / 32, D / 32), blk, 0, stream>>>(ca_wk, wt_cak, D, D);
    wtrans_kernel<<<dim3(D / 32, D / 32), blk, 0, stream>>>(ca_wv, wt_cav, D, D);
    wtrans_kernel<<<dim3(D / 32, D / 32), blk, 0, stream>>>(ca_wo, wt_cao, D, D);
    wtrans_kernel<<<dim3(DFF / 32, D / 32), blk, 0, stream>>>(ff_w1, wt_ff1, D, DFF);
    wtrans_kernel<<<dim3(D / 32, DFF / 32), blk, 0, stream>>>(ff_w2, wt_ff2, DFF, D);
    cvt_kernel<<<dim3(M * D / 1024), blk, 0, stream>>>(enc, encb, M * D);

    // ---- block 1: self-attention ----
    ln_kernel<<<dim3(M), blk, 0, stream>>>(x, n1_g, n1_b, hb);
    gemm_kernel<1><<<dim3(D / 128, M / 128), blk, 0, stream>>>(hb, wt_saq, sa_bq, nullptr, nullptr, qbuf, M, D, D);
    gemm_kernel<1><<<dim3(D / 128, M / 128), blk, 0, stream>>>(hb, wt_sak, sa_bk, nullptr, nullptr, kbuf, M, D, D);
    gemm_kernel<1><<<dim3(D / 128, M / 128), blk, 0, stream>>>(hb, wt_sav, sa_bv, nullptr, nullptr, vbuf, M, D, D);
    attn_kernel<true><<<dim3(S / 64, B * 16), blk, 0, stream>>>(qbuf, kbuf, vbuf, abuf);
    gemm_kernel<3><<<dim3(D / 128, M / 128), blk, 0, stream>>>(abuf, wt_sao, sa_bo, x, x1, nullptr, M, D, D);

    // ---- block 2: cross-attention ----
    ln_kernel<<<dim3(M), blk, 0, stream>>>(x1, n2_g, n2_b, hb);
    gemm_kernel<1><<<dim3(D / 128, M / 128), blk, 0, stream>>>(hb, wt_caq, ca_bq, nullptr, nullptr, qbuf, M, D, D);
    gemm_kernel<1><<<dim3(D / 128, M / 128), blk, 0, stream>>>(encb, wt_cak, ca_bk, nullptr, nullptr, kbuf, M, D, D);
    gemm_kernel<1><<<dim3(D / 128, M / 128), blk, 0, stream>>>(encb, wt_cav, ca_bv, nullptr, nullptr, vbuf, M, D, D);
    attn_kernel<false><<<dim3(S / 64, B * 16), blk, 0, stream>>>(qbuf, kbuf, vbuf, abuf);
    gemm_kernel<3><<<dim3(D / 128, M / 128), blk, 0, stream>>>(abuf, wt_cao, ca_bo, x1, x2, nullptr, M, D, D);

    // ---- block 3: feed-forward ----
    ln_kernel<<<dim3(M), blk, 0, stream>>>(x2, n3_g, n3_b, hb);
    gemm_kernel<2><<<dim3(DFF / 128, M / 128), blk, 0, stream>>>(hb, wt_ff1, ff_b1, nullptr, nullptr, ffh, M, DFF, D);
    gemm_kernel<3><<<dim3(D / 128, M / 128), blk, 0, stream>>>(ffh, wt_ff2, ff_b2, x2, out, nullptr, M, D, DFF);
}

// Round 4
// 765.607 us; speedup vs baseline: 1.1794x; 1.1794x over previous
//
#include <hip/hip_runtime.h>

typedef short short8 __attribute__((ext_vector_type(8)));
typedef float f32x4 __attribute__((ext_vector_type(4)));

#define LDK 40   // padded LDS K-stride for GEMM tiles
#define SEQ 2048
#define QSCALE 0.18033688011112042f   // 0.125 * log2(e): softmax done in base 2
#define EXP2(x) __builtin_amdgcn_exp2f(x)

__device__ __forceinline__ unsigned short f2bf(float f) {
    unsigned int u = __builtin_bit_cast(unsigned int, f);
    unsigned int r = (u + 0x7fffu + ((u >> 16) & 1u)) >> 16;
    return (unsigned short)r;
}

// ---------------------------------------------------------------------------
// Weight transpose + fp32->bf16 convert:  Wt[n*K + k] = bf16(W[k*N + n])
// ---------------------------------------------------------------------------
__global__ __launch_bounds__(256)
void wtrans_kernel(const float* __restrict__ W, unsigned short* __restrict__ Wt,
                   int Kd, int Nd)
{
    __shared__ float t[32][33];
    const int tx = threadIdx.x & 31;
    const int ty = threadIdx.x >> 5;
    const int nb = blockIdx.x * 32;
    const int kb = blockIdx.y * 32;
#pragma unroll
    for (int i = 0; i < 4; i++)
        t[ty + i * 8][tx] = W[(size_t)(kb + ty + i * 8) * Nd + nb + tx];
    __syncthreads();
#pragma unroll
    for (int i = 0; i < 4; i++)
        Wt[(size_t)(nb + ty + i * 8) * Kd + kb + tx] = f2bf(t[tx][ty + i * 8]);
}

// ---------------------------------------------------------------------------
// Elementwise fp32 -> bf16
// ---------------------------------------------------------------------------
__global__ __launch_bounds__(256)
void cvt_kernel(const float* __restrict__ in, unsigned short* __restrict__ out, int n)
{
    int i = (blockIdx.x * 256 + threadIdx.x) * 4;
    if (i < n) {
        float4 v = *(const float4*)(in + i);
        ushort4 o;
        o.x = f2bf(v.x); o.y = f2bf(v.y); o.z = f2bf(v.z); o.w = f2bf(v.w);
        *(ushort4*)(out + i) = o;
    }
}

// ---------------------------------------------------------------------------
// bf16 transpose within each (b,h): V [BH][S][64] -> VT [BH][64][S]
// ---------------------------------------------------------------------------
__global__ __launch_bounds__(256)
void vtrans_kernel(const unsigned short* __restrict__ V, unsigned short* __restrict__ VT)
{
    __shared__ unsigned short t[64][72];
    const int tid = threadIdx.x;
    const int bh = blockIdx.y;
    const int s0 = blockIdx.x * 64;
    const int r4  = tid >> 2;        // 0..63
    const int c16 = (tid & 3) * 16;  // 0,16,32,48
    const unsigned short* src = V + (size_t)bh * SEQ * 64 + (size_t)(s0 + r4) * 64;
    *(short8*)&t[r4][c16]     = *(const short8*)(src + c16);
    *(short8*)&t[r4][c16 + 8] = *(const short8*)(src + c16 + 8);
    __syncthreads();
    short8 a, b;
#pragma unroll
    for (int j = 0; j < 8; j++) { a[j] = t[c16 + j][r4]; b[j] = t[c16 + 8 + j][r4]; }
    unsigned short* dst = VT + (size_t)bh * 64 * SEQ + (size_t)r4 * SEQ + s0 + c16;
    *(short8*)dst = a;
    *(short8*)(dst + 8) = b;
}

// ---------------------------------------------------------------------------
// LayerNorm (torch-faithful: ddof=1, eps added to std). fp32 in -> bf16 out.
// ---------------------------------------------------------------------------
__global__ __launch_bounds__(256)
void ln_kernel(const float* __restrict__ x, const float* __restrict__ g,
               const float* __restrict__ bb, unsigned short* __restrict__ out)
{
    const int D = 1024;
    const int row = blockIdx.x;
    const float* xr = x + (size_t)row * D;
    float v[4];
    float s = 0.f, ss = 0.f;
#pragma unroll
    for (int i = 0; i < 4; i++) {
        v[i] = xr[threadIdx.x + i * 256];
        s += v[i];
        ss += v[i] * v[i];
    }
#pragma unroll
    for (int off = 1; off < 64; off <<= 1) {
        s  += __shfl_xor(s,  off, 64);
        ss += __shfl_xor(ss, off, 64);
    }
    __shared__ float red[8];
    const int wave = threadIdx.x >> 6;
    if ((threadIdx.x & 63) == 0) { red[wave] = s; red[4 + wave] = ss; }
    __syncthreads();
    s  = red[0] + red[1] + red[2] + red[3];
    ss = red[4] + red[5] + red[6] + red[7];
    float mean = s / D;
    float var  = fmaxf((ss - s * mean) / (D - 1), 0.f);
    float inv  = 1.f / (sqrtf(var) + 1e-6f);
#pragma unroll
    for (int i = 0; i < 4; i++) {
        int c = threadIdx.x + i * 256;
        out[(size_t)row * D + c] = f2bf(g[c] * (v[i] - mean) * inv + bb[c]);
    }
}

// ---------------------------------------------------------------------------
// Tiled MFMA GEMM: C[M,N] = A[M,K] @ Wt[N,K]^T + bias
// MODE 1: multi-section head-scatter (QKV / KV / Q projections).
//   global sect = SECT_OFF + (n0>>10): 0 -> o0 (Q, scaled by QSCALE),
//   1 -> o1 (K), 2 -> o2 (V); all stored [B,H,S,64] bf16.
// MODE 2: relu -> bf16 out row-major [M,N]   (FFN first GEMM, o0)
// MODE 3: + res (fp32) -> fp32 out row-major (output projections, outf)
// ---------------------------------------------------------------------------
template <int MODE, int SECT_OFF>
__global__ __launch_bounds__(256)
void gemm_kernel(const unsigned short* __restrict__ A,
                 const unsigned short* __restrict__ Wt,
                 const float* __restrict__ b0,
                 const float* __restrict__ b1,
                 const float* __restrict__ b2,
                 const float* __restrict__ res,
                 float* __restrict__ outf,
                 unsigned short* __restrict__ o0,
                 unsigned short* __restrict__ o1,
                 unsigned short* __restrict__ o2,
                 int M, int N, int K)
{
    __shared__ unsigned short As[128 * LDK];
    __shared__ unsigned short Bs[128 * LDK];
    const int tid  = threadIdx.x;
    const int lane = tid & 63;
    const int wave = tid >> 6;
    const int quad = lane >> 4;
    const int l16  = lane & 15;
    const int m0 = blockIdx.y * 128;
    const int n0 = blockIdx.x * 128;
    const int wm = (wave >> 1) << 6;
    const int wn = (wave & 1) << 6;
    const int srow = tid >> 1;
    const int scol = (tid & 1) << 4;

    f32x4 acc[4][4];
#pragma unroll
    for (int i = 0; i < 4; i++)
#pragma unroll
        for (int j = 0; j < 4; j++) acc[i][j] = f32x4{0.f, 0.f, 0.f, 0.f};

    const unsigned short* Ag = A  + (size_t)(m0 + srow) * K + scol;
    const unsigned short* Bg = Wt + (size_t)(n0 + srow) * K + scol;
    unsigned short* Asw = &As[srow * LDK + scol];
    unsigned short* Bsw = &Bs[srow * LDK + scol];

    for (int k0 = 0; k0 < K; k0 += 32) {
        short8 a0 = *(const short8*)(Ag + k0);
        short8 a1 = *(const short8*)(Ag + k0 + 8);
        short8 b0v = *(const short8*)(Bg + k0);
        short8 b1v = *(const short8*)(Bg + k0 + 8);
        *(short8*)(Asw)     = a0;
        *(short8*)(Asw + 8) = a1;
        *(short8*)(Bsw)     = b0v;
        *(short8*)(Bsw + 8) = b1v;
        __syncthreads();
        short8 af[4], bfr[4];
#pragma unroll
        for (int i = 0; i < 4; i++)
            af[i] = *(const short8*)(&As[(wm + i * 16 + l16) * LDK + quad * 8]);
#pragma unroll
        for (int i = 0; i < 4; i++)
            bfr[i] = *(const short8*)(&Bs[(wn + i * 16 + l16) * LDK + quad * 8]);
#pragma unroll
        for (int mi = 0; mi < 4; mi++)
#pragma unroll
            for (int ni = 0; ni < 4; ni++)
                acc[mi][ni] = __builtin_amdgcn_mfma_f32_16x16x32_bf16(
                    af[mi], bfr[ni], acc[mi][ni], 0, 0, 0);
        __syncthreads();
    }

    if (MODE == 1) {
        const int sect = SECT_OFF + (n0 >> 10);
        const float* bias = (sect == 0) ? b0 : ((sect == 1) ? b1 : b2);
        unsigned short* dst = (sect == 0) ? o0 : ((sect == 1) ? o1 : o2);
        const float scl = (sect == 0) ? QSCALE : 1.0f;
#pragma unroll
        for (int mi = 0; mi < 4; mi++)
#pragma unroll
            for (int ni = 0; ni < 4; ni++) {
                const int colg = n0 + wn + ni * 16 + l16;
                const int cc = colg & 1023;
                const int h = cc >> 6, d = cc & 63;
                const float bv = bias[cc];
#pragma unroll
                for (int r = 0; r < 4; r++) {
                    const int rowg = m0 + wm + mi * 16 + quad * 4 + r;
                    const int b = rowg >> 11, s = rowg & 2047;
                    float v = (acc[mi][ni][r] + bv) * scl;
                    dst[((size_t)(b * 16 + h) * SEQ + s) * 64 + d] = f2bf(v);
                }
            }
    } else {
#pragma unroll
        for (int mi = 0; mi < 4; mi++)
#pragma unroll
            for (int ni = 0; ni < 4; ni++) {
                const int colg = n0 + wn + ni * 16 + l16;
                const float bv = b0[colg];
#pragma unroll
                for (int r = 0; r < 4; r++) {
                    const int rowg = m0 + wm + mi * 16 + quad * 4 + r;
                    float v = acc[mi][ni][r] + bv;
                    if (MODE == 2) {
                        o0[(size_t)rowg * N + colg] = f2bf(fmaxf(v, 0.f));
                    } else {
                        outf[(size_t)rowg * N + colg] = v + res[(size_t)rowg * N + colg];
                    }
                }
            }
    }
}

// ---------------------------------------------------------------------------
// Flash attention v2. Q (pre-scaled by QSCALE), K: [B,H,S,64] bf16.
// VT: [B,H,64,S] bf16 (pre-transposed). O: [B,S,1024] bf16.
// Block = 256 threads / 4 waves; 64 queries per block (16 per wave);
// 128-key tiles; softmax in base 2; PV computed as O^T = V^T @ P^T so both
// fragments are contiguous b128 LDS reads and the epilogue is ushort4 stores.
// ---------------------------------------------------------------------------
template <bool CAUSAL>
__global__ __launch_bounds__(256)
void attn2_kernel(const unsigned short* __restrict__ Q,
                  const unsigned short* __restrict__ K,
                  const unsigned short* __restrict__ VT,
                  unsigned short* __restrict__ O)
{
    __shared__ unsigned short Ks[128 * 72];     // [key][d]
    __shared__ unsigned short Vt[64 * 136];     // [d][key]
    __shared__ unsigned short Ps[4][16 * 136];  // per-wave [q][key]
    __shared__ float alphaS[4][16];
    __shared__ float sumS[4][16];
    const int tid  = threadIdx.x;
    const int lane = tid & 63;
    const int wave = tid >> 6;
    const int quad = lane >> 4;
    const int l16  = lane & 15;
    const int bh = blockIdx.y;
    const int qb = blockIdx.x;
    const int q0 = qb * 64;
    const size_t baseK = (size_t)bh * SEQ * 64;   // Q/K layout
    const size_t baseV = (size_t)bh * 64 * SEQ;   // VT layout

    short8 aq[2];
    {
        const unsigned short* qp = Q + baseK + (size_t)(q0 + wave * 16 + l16) * 64 + quad * 8;
        aq[0] = *(const short8*)(qp);
        aq[1] = *(const short8*)(qp + 32);
    }
    f32x4 acc[4];   // O^T: row d = mi*16+quad*4+r, col q = l16
#pragma unroll
    for (int i = 0; i < 4; i++) acc[i] = f32x4{0.f, 0.f, 0.f, 0.f};
    float m_i[4], l_i[4];
#pragma unroll
    for (int r = 0; r < 4; r++) { m_i[r] = -3.0e38f; l_i[r] = 0.f; }

    const int nkb = CAUSAL ? ((qb >> 1) + 1) : (SEQ / 128);
    const int krow = tid >> 1;          // 0..127
    const int kc   = (tid & 1) * 32;    // 0 / 32
    const int vrow = tid >> 2;          // 0..63
    const int vc   = (tid & 3) * 32;    // 0..96

    for (int kb = 0; kb < nkb; kb++) {
        const int k0 = kb * 128;
        __syncthreads();   // protect LDS from previous iteration's readers
        {
            const unsigned short* kp = K + baseK + (size_t)(k0 + krow) * 64 + kc;
            *(short8*)&Ks[krow * 72 + kc]      = *(const short8*)(kp);
            *(short8*)&Ks[krow * 72 + kc + 8]  = *(const short8*)(kp + 8);
            *(short8*)&Ks[krow * 72 + kc + 16] = *(const short8*)(kp + 16);
            *(short8*)&Ks[krow * 72 + kc + 24] = *(const short8*)(kp + 24);
            const unsigned short* vp = VT + baseV + (size_t)vrow * SEQ + k0 + vc;
            *(short8*)&Vt[vrow * 136 + vc]      = *(const short8*)(vp);
            *(short8*)&Vt[vrow * 136 + vc + 8]  = *(const short8*)(vp + 8);
            *(short8*)&Vt[vrow * 136 + vc + 16] = *(const short8*)(vp + 16);
            *(short8*)&Vt[vrow * 136 + vc + 24] = *(const short8*)(vp + 24);
        }
        __syncthreads();

        // S = Q K^T : C-layout row q=quad*4+r, col key=nt*16+l16
        f32x4 scf[8];
#pragma unroll
        for (int nt = 0; nt < 8; nt++) {
            f32x4 z = f32x4{0.f, 0.f, 0.f, 0.f};
#pragma unroll
            for (int c = 0; c < 2; c++) {
                short8 bk = *(const short8*)(&Ks[(nt * 16 + l16) * 72 + c * 32 + quad * 8]);
                z = __builtin_amdgcn_mfma_f32_16x16x32_bf16(aq[c], bk, z, 0, 0, 0);
            }
            scf[nt] = z;
        }
        if (CAUSAL) {
            const int qg = q0 + wave * 16 + quad * 4;
#pragma unroll
            for (int nt = 0; nt < 8; nt++) {
                const int kg = k0 + nt * 16 + l16;
#pragma unroll
                for (int r = 0; r < 4; r++)
                    if (kg > qg + r) scf[nt][r] = -1e9f;
            }
        }
        // online softmax (base 2), rows quad*4+r over 16 lanes (l16 = key)
        float alr[4];
#pragma unroll
        for (int r = 0; r < 4; r++) {
            float mx = scf[0][r];
#pragma unroll
            for (int nt = 1; nt < 8; nt++) mx = fmaxf(mx, scf[nt][r]);
#pragma unroll
            for (int off = 1; off < 16; off <<= 1) mx = fmaxf(mx, __shfl_xor(mx, off, 64));
            float mnew = fmaxf(m_i[r], mx);
            alr[r] = EXP2(m_i[r] - mnew);
            m_i[r] = mnew;
            float rs = 0.f;
#pragma unroll
            for (int nt = 0; nt < 8; nt++) {
                float pv = EXP2(scf[nt][r] - mnew);
                scf[nt][r] = pv;
                rs += pv;
            }
#pragma unroll
            for (int off = 1; off < 16; off <<= 1) rs += __shfl_xor(rs, off, 64);
            l_i[r] = l_i[r] * alr[r] + rs;
        }
        if (l16 == 0) {
#pragma unroll
            for (int r = 0; r < 4; r++) alphaS[wave][quad * 4 + r] = alr[r];
        }
        // P -> LDS (own wave only; within-wave DS ordering, no barrier needed)
#pragma unroll
        for (int nt = 0; nt < 8; nt++)
#pragma unroll
            for (int r = 0; r < 4; r++)
                Ps[wave][(quad * 4 + r) * 136 + nt * 16 + l16] = f2bf(scf[nt][r]);
        const float aQ = alphaS[wave][l16];
#pragma unroll
        for (int mi = 0; mi < 4; mi++) {
            acc[mi][0] *= aQ; acc[mi][1] *= aQ; acc[mi][2] *= aQ; acc[mi][3] *= aQ;
        }
        // O^T += V^T @ P^T : A = Vt (b128), B = Ps rows (b128)
#pragma unroll
        for (int c = 0; c < 4; c++) {
            short8 bp = *(const short8*)(&Ps[wave][l16 * 136 + c * 32 + quad * 8]);
#pragma unroll
            for (int mi = 0; mi < 4; mi++) {
                short8 av = *(const short8*)(&Vt[(mi * 16 + l16) * 136 + c * 32 + quad * 8]);
                acc[mi] = __builtin_amdgcn_mfma_f32_16x16x32_bf16(av, bp, acc[mi], 0, 0, 0);
            }
        }
    }
    if (l16 == 0) {
#pragma unroll
        for (int r = 0; r < 4; r++) sumS[wave][quad * 4 + r] = l_i[r];
    }
    __syncthreads();
    const float rcpL = 1.f / sumS[wave][l16];
    const int b = bh >> 4, h = bh & 15;
    const int qg = q0 + wave * 16 + l16;
#pragma unroll
    for (int mi = 0; mi < 4; mi++) {
        ushort4 o4;
        o4.x = f2bf(acc[mi][0] * rcpL);
        o4.y = f2bf(acc[mi][1] * rcpL);
        o4.z = f2bf(acc[mi][2] * rcpL);
        o4.w = f2bf(acc[mi][3] * rcpL);
        *(ushort4*)&O[(size_t)(b * SEQ + qg) * 1024 + h * 64 + mi * 16 + quad * 4] = o4;
    }
}

// ---------------------------------------------------------------------------
extern "C" void kernel_launch(void* const* d_in, const int* in_sizes, int n_in,
                              void* d_out, int out_size, void* d_ws, size_t ws_size,
                              hipStream_t stream)
{
    (void)in_sizes; (void)n_in; (void)out_size; (void)ws_size;
    const int B = 2, S = SEQ, D = 1024, DFF = 4096;
    const int M = B * S;  // 4096

    const float* x     = (const float*)d_in[0];
    const float* enc   = (const float*)d_in[1];
    const float* sa_wq = (const float*)d_in[4],  *sa_bq = (const float*)d_in[5];
    const float* sa_wk = (const float*)d_in[6],  *sa_bk = (const float*)d_in[7];
    const float* sa_wv = (const float*)d_in[8],  *sa_bv = (const float*)d_in[9];
    const float* sa_wo = (const float*)d_in[10], *sa_bo = (const float*)d_in[11];
    const float* ca_wq = (const float*)d_in[12], *ca_bq = (const float*)d_in[13];
    const float* ca_wk = (const float*)d_in[14], *ca_bk = (const float*)d_in[15];
    const float* ca_wv = (const float*)d_in[16], *ca_bv = (const float*)d_in[17];
    const float* ca_wo = (const float*)d_in[18], *ca_bo = (const float*)d_in[19];
    const float* ff_w1 = (const float*)d_in[20], *ff_b1 = (const float*)d_in[21];
    const float* ff_w2 = (const float*)d_in[22], *ff_b2 = (const float*)d_in[23];
    const float* n1_g  = (const float*)d_in[24], *n1_b = (const float*)d_in[25];
    const float* n2_g  = (const float*)d_in[26], *n2_b = (const float*)d_in[27];
    const float* n3_g  = (const float*)d_in[28], *n3_b = (const float*)d_in[29];
    float* out = (float*)d_out;

    char* p = (char*)d_ws;
    auto carve = [&](size_t bytes) -> char* {
        char* r = p;
        p += (bytes + 255) & ~(size_t)255;
        return r;
    };
    unsigned short* wt_sqkv = (unsigned short*)carve((size_t)3 * D * D * 2); // [3072][1024]
    unsigned short* wt_sao  = (unsigned short*)carve((size_t)D * D * 2);
    unsigned short* wt_caq  = (unsigned short*)carve((size_t)D * D * 2);
    unsigned short* wt_cakv = (unsigned short*)carve((size_t)2 * D * D * 2); // [2048][1024]
    unsigned short* wt_cao  = (unsigned short*)carve((size_t)D * D * 2);
    unsigned short* wt_ff1  = (unsigned short*)carve((size_t)D * DFF * 2);
    unsigned short* wt_ff2  = (unsigned short*)carve((size_t)DFF * D * 2);
    unsigned short* encb    = (unsigned short*)carve((size_t)M * D * 2);
    unsigned short* hb      = (unsigned short*)carve((size_t)M * D * 2);
    unsigned short* qbuf    = (unsigned short*)carve((size_t)M * D * 2);
    unsigned short* kbuf    = (unsigned short*)carve((size_t)M * D * 2);
    unsigned short* vbuf    = (unsigned short*)carve((size_t)M * D * 2);
    unsigned short* vtbuf   = (unsigned short*)carve((size_t)M * D * 2);
    unsigned short* ffh     = (unsigned short*)carve((size_t)M * DFF * 2);
    float* x1 = (float*)carve((size_t)M * D * 4);
    unsigned short* abuf = hb;   // lifetimes disjoint
    float* x2 = out;             // block-2 residual in d_out; block-3 in-place

    dim3 blk(256);
    // weight pre-pass
    wtrans_kernel<<<dim3(D / 32, D / 32), blk, 0, stream>>>(sa_wq, wt_sqkv, D, D);
    wtrans_kernel<<<dim3(D / 32, D / 32), blk, 0, stream>>>(sa_wk, wt_sqkv + (size_t)D * D, D, D);
    wtrans_kernel<<<dim3(D / 32, D / 32), blk, 0, stream>>>(sa_wv, wt_sqkv + (size_t)2 * D * D, D, D);
    wtrans_kernel<<<dim3(D / 32, D / 32), blk, 0, stream>>>(sa_wo, wt_sao, D, D);
    wtrans_kernel<<<dim3(D / 32, D / 32), blk, 0, stream>>>(ca_wq, wt_caq, D, D);
    wtrans_kernel<<<dim3(D / 32, D / 32), blk, 0, stream>>>(ca_wk, wt_cakv, D, D);
    wtrans_kernel<<<dim3(D / 32, D / 32), blk, 0, stream>>>(ca_wv, wt_cakv + (size_t)D * D, D, D);
    wtrans_kernel<<<dim3(D / 32, D / 32), blk, 0, stream>>>(ca_wo, wt_cao, D, D);
    wtrans_kernel<<<dim3(DFF / 32, D / 32), blk, 0, stream>>>(ff_w1, wt_ff1, D, DFF);
    wtrans_kernel<<<dim3(D / 32, DFF / 32), blk, 0, stream>>>(ff_w2, wt_ff2, DFF, D);
    cvt_kernel<<<dim3(M * D / 1024), blk, 0, stream>>>(enc, encb, M * D);

    // ---- block 1: self-attention ----
    ln_kernel<<<dim3(M), blk, 0, stream>>>(x, n1_g, n1_b, hb);
    gemm_kernel<1, 0><<<dim3(3 * D / 128, M / 128), blk, 0, stream>>>(
        hb, wt_sqkv, sa_bq, sa_bk, sa_bv, nullptr, nullptr, qbuf, kbuf, vbuf, M, 3 * D, D);
    vtrans_kernel<<<dim3(S / 64, B * 16), blk, 0, stream>>>(vbuf, vtbuf);
    attn2_kernel<true><<<dim3(S / 64, B * 16), blk, 0, stream>>>(qbuf, kbuf, vtbuf, abuf);
    gemm_kernel<3, 0><<<dim3(D / 128, M / 128), blk, 0, stream>>>(
        abuf, wt_sao, sa_bo, nullptr, nullptr, x, x1, nullptr, nullptr, nullptr, M, D, D);

    // ---- block 2: cross-attention ----
    ln_kernel<<<dim3(M), blk, 0, stream>>>(x1, n2_g, n2_b, hb);
    gemm_kernel<1, 0><<<dim3(D / 128, M / 128), blk, 0, stream>>>(
        hb, wt_caq, ca_bq, nullptr, nullptr, nullptr, nullptr, qbuf, nullptr, nullptr, M, D, D);
    gemm_kernel<1, 1><<<dim3(2 * D / 128, M / 128), blk, 0, stream>>>(
        encb, wt_cakv, nullptr, ca_bk, ca_bv, nullptr, nullptr, nullptr, kbuf, vbuf, M, 2 * D, D);
    vtrans_kernel<<<dim3(S / 64, B * 16), blk, 0, stream>>>(vbuf, vtbuf);
    attn2_kernel<false><<<dim3(S / 64, B * 16), blk, 0, stream>>>(qbuf, kbuf, vtbuf, abuf);
    gemm_kernel<3, 0><<<dim3(D / 128, M / 128), blk, 0, stream>>>(
        abuf, wt_cao, ca_bo, nullptr, nullptr, x1, x2, nullptr, nullptr, nullptr, M, D, D);

    // ---- block 3: feed-forward ----
    ln_kernel<<<dim3(M), blk, 0, stream>>>(x2, n3_g, n3_b, hb);
    gemm_kernel<2, 0><<<dim3(DFF / 128, M / 128), blk, 0, stream>>>(
        hb, wt_ff1, ff_b1, nullptr, nullptr, nullptr, nullptr, ffh, nullptr, nullptr, M, DFF, D);
    gemm_kernel<3, 0><<<dim3(D / 128, M / 128), blk, 0, stream>>>(
        ffh, wt_ff2, ff_b2, nullptr, nullptr, x2, out, nullptr, nullptr, nullptr, M, D, DFF);
}

// Round 5
// 675.111 us; speedup vs baseline: 1.3375x; 1.1340x over previous
//
#include <hip/hip_runtime.h>

typedef short short8 __attribute__((ext_vector_type(8)));
typedef float f32x4 __attribute__((ext_vector_type(4)));

#define SEQ 2048
#define QSCALE 0.18033688011112042f   // 0.125 * log2(e): softmax done in base 2
#define PSHIFT 20.0f                  // fixed softmax shift (cancels in O = acc/l)
#define EXP2(x) __builtin_amdgcn_exp2f(x)

// async global->LDS, 16B per lane; lds base must be wave-uniform
#define GLDS(g, l) __builtin_amdgcn_global_load_lds( \
    (const __attribute__((address_space(1))) unsigned int*)(g), \
    (__attribute__((address_space(3))) unsigned int*)(l), 16, 0, 0)

__device__ __forceinline__ unsigned short f2bf(float f) {
    unsigned int u = __builtin_bit_cast(unsigned int, f);
    unsigned int r = (u + 0x7fffu + ((u >> 16) & 1u)) >> 16;
    return (unsigned short)r;
}

// ---------------------------------------------------------------------------
// Batched weight transpose + fp32->bf16: 8 D x D weights in one launch.
// out[z] [n*1024 + k] = bf16(W_z[k*1024 + n])
// ---------------------------------------------------------------------------
__global__ __launch_bounds__(256)
void wtrans8_kernel(const float* w0, const float* w1, const float* w2, const float* w3,
                    const float* w4, const float* w5, const float* w6, const float* w7,
                    unsigned short* __restrict__ outbase)
{
    const float* Ws[8] = {w0, w1, w2, w3, w4, w5, w6, w7};
    const float* __restrict__ W = Ws[blockIdx.z];
    unsigned short* __restrict__ Wt = outbase + (size_t)blockIdx.z * 1024 * 1024;
    __shared__ float t[32][33];
    const int tx = threadIdx.x & 31;
    const int ty = threadIdx.x >> 5;
    const int nb = blockIdx.x * 32;
    const int kb = blockIdx.y * 32;
#pragma unroll
    for (int i = 0; i < 4; i++)
        t[ty + i * 8][tx] = W[(size_t)(kb + ty + i * 8) * 1024 + nb + tx];
    __syncthreads();
#pragma unroll
    for (int i = 0; i < 4; i++)
        Wt[(size_t)(nb + ty + i * 8) * 1024 + kb + tx] = f2bf(t[tx][ty + i * 8]);
}

// single weight transpose (for the two FFN shapes)
__global__ __launch_bounds__(256)
void wtrans_kernel(const float* __restrict__ W, unsigned short* __restrict__ Wt,
                   int Kd, int Nd)
{
    __shared__ float t[32][33];
    const int tx = threadIdx.x & 31;
    const int ty = threadIdx.x >> 5;
    const int nb = blockIdx.x * 32;
    const int kb = blockIdx.y * 32;
#pragma unroll
    for (int i = 0; i < 4; i++)
        t[ty + i * 8][tx] = W[(size_t)(kb + ty + i * 8) * Nd + nb + tx];
    __syncthreads();
#pragma unroll
    for (int i = 0; i < 4; i++)
        Wt[(size_t)(nb + ty + i * 8) * Kd + kb + tx] = f2bf(t[tx][ty + i * 8]);
}

// ---------------------------------------------------------------------------
// Elementwise fp32 -> bf16
// ---------------------------------------------------------------------------
__global__ __launch_bounds__(256)
void cvt_kernel(const float* __restrict__ in, unsigned short* __restrict__ out, int n)
{
    int i = (blockIdx.x * 256 + threadIdx.x) * 4;
    if (i < n) {
        float4 v = *(const float4*)(in + i);
        ushort4 o;
        o.x = f2bf(v.x); o.y = f2bf(v.y); o.z = f2bf(v.z); o.w = f2bf(v.w);
        *(ushort4*)(out + i) = o;
    }
}

// ---------------------------------------------------------------------------
// bf16 transpose within each (b,h): V [BH][S][64] -> VT [BH][64][S]
// ---------------------------------------------------------------------------
__global__ __launch_bounds__(256)
void vtrans_kernel(const unsigned short* __restrict__ V, unsigned short* __restrict__ VT)
{
    __shared__ unsigned short t[64][72];
    const int tid = threadIdx.x;
    const int bh = blockIdx.y;
    const int s0 = blockIdx.x * 64;
    const int r4  = tid >> 2;
    const int c16 = (tid & 3) * 16;
    const unsigned short* src = V + (size_t)bh * SEQ * 64 + (size_t)(s0 + r4) * 64;
    *(short8*)&t[r4][c16]     = *(const short8*)(src + c16);
    *(short8*)&t[r4][c16 + 8] = *(const short8*)(src + c16 + 8);
    __syncthreads();
    short8 a, b;
#pragma unroll
    for (int j = 0; j < 8; j++) { a[j] = t[c16 + j][r4]; b[j] = t[c16 + 8 + j][r4]; }
    unsigned short* dst = VT + (size_t)bh * 64 * SEQ + (size_t)r4 * SEQ + s0 + c16;
    *(short8*)dst = a;
    *(short8*)(dst + 8) = b;
}

// ---------------------------------------------------------------------------
// LayerNorm (torch-faithful: ddof=1, eps added to std). fp32 in -> bf16 out.
// ---------------------------------------------------------------------------
__global__ __launch_bounds__(256)
void ln_kernel(const float* __restrict__ x, const float* __restrict__ g,
               const float* __restrict__ bb, unsigned short* __restrict__ out)
{
    const int D = 1024;
    const int row = blockIdx.x;
    const float* xr = x + (size_t)row * D;
    float v[4];
    float s = 0.f, ss = 0.f;
#pragma unroll
    for (int i = 0; i < 4; i++) {
        v[i] = xr[threadIdx.x + i * 256];
        s += v[i];
        ss += v[i] * v[i];
    }
#pragma unroll
    for (int off = 1; off < 64; off <<= 1) {
        s  += __shfl_xor(s,  off, 64);
        ss += __shfl_xor(ss, off, 64);
    }
    __shared__ float red[8];
    const int wave = threadIdx.x >> 6;
    if ((threadIdx.x & 63) == 0) { red[wave] = s; red[4 + wave] = ss; }
    __syncthreads();
    s  = red[0] + red[1] + red[2] + red[3];
    ss = red[4] + red[5] + red[6] + red[7];
    float mean = s / D;
    float var  = fmaxf((ss - s * mean) / (D - 1), 0.f);
    float inv  = 1.f / (sqrtf(var) + 1e-6f);
#pragma unroll
    for (int i = 0; i < 4; i++) {
        int c = threadIdx.x + i * 256;
        out[(size_t)row * D + c] = f2bf(g[c] * (v[i] - mean) * inv + bb[c]);
    }
}

// ---------------------------------------------------------------------------
// Tiled MFMA GEMM (m97 structure): C[M,N] = A[M,K] @ Wt[N,K]^T + bias
// 128x128 tile, BK=32, unpadded LDS, global_load_lds 16B async staging.
// MODE 1: multi-section head-scatter (QKV/KV/Q proj) -> [B,H,S,64] bf16,
//         section 0 (Q) scaled by QSCALE.
// MODE 2: relu -> bf16 row-major [M,N]    (FFN first GEMM, o0)
// MODE 3: + res (fp32) -> fp32 row-major  (output projections, outf)
// ---------------------------------------------------------------------------
template <int MODE, int SECT_OFF>
__global__ __launch_bounds__(256)
void gemm_kernel(const unsigned short* __restrict__ A,
                 const unsigned short* __restrict__ Wt,
                 const float* __restrict__ b0,
                 const float* __restrict__ b1,
                 const float* __restrict__ b2,
                 const float* __restrict__ res,
                 float* __restrict__ outf,
                 unsigned short* __restrict__ o0,
                 unsigned short* __restrict__ o1,
                 unsigned short* __restrict__ o2,
                 int M, int N, int K)
{
    __shared__ unsigned short As[128 * 32];
    __shared__ unsigned short Bs[128 * 32];
    const int tid  = threadIdx.x;
    const int lane = tid & 63;
    const int wv   = tid >> 6;
    const int quad = lane >> 4;
    const int l16  = lane & 15;
    const int m0 = blockIdx.y * 128;
    const int n0 = blockIdx.x * 128;
    const int wm = (wv >> 1) << 6;
    const int wn = (wv & 1) << 6;

    // staging map: wave w issue i covers LDS u16 [(w*2+i)*512, +512):
    //   lane l -> row (w*2+i)*16 + l/4, col (l&3)*8  (16B each)
    const int srow0 = wv * 32 + (lane >> 2);
    const int srow1 = srow0 + 16;
    const int scol8 = (lane & 3) * 8;
    unsigned short* asw0 = &As[(wv * 2 + 0) * 512];
    unsigned short* asw1 = &As[(wv * 2 + 1) * 512];
    unsigned short* bsw0 = &Bs[(wv * 2 + 0) * 512];
    unsigned short* bsw1 = &Bs[(wv * 2 + 1) * 512];
    const unsigned short* Ag0 = A  + (size_t)(m0 + srow0) * K + scol8;
    const unsigned short* Ag1 = A  + (size_t)(m0 + srow1) * K + scol8;
    const unsigned short* Bg0 = Wt + (size_t)(n0 + srow0) * K + scol8;
    const unsigned short* Bg1 = Wt + (size_t)(n0 + srow1) * K + scol8;

    f32x4 acc[4][4];
#pragma unroll
    for (int i = 0; i < 4; i++)
#pragma unroll
        for (int j = 0; j < 4; j++) acc[i][j] = f32x4{0.f, 0.f, 0.f, 0.f};

    for (int k0 = 0; k0 < K; k0 += 32) {
        GLDS(Ag0 + k0, asw0);
        GLDS(Ag1 + k0, asw1);
        GLDS(Bg0 + k0, bsw0);
        GLDS(Bg1 + k0, bsw1);
        __syncthreads();   // drains vmcnt -> staging complete
        short8 af[4], bfr[4];
#pragma unroll
        for (int i = 0; i < 4; i++)
            af[i] = *(const short8*)(&As[(wm + i * 16 + l16) * 32 + quad * 8]);
#pragma unroll
        for (int i = 0; i < 4; i++)
            bfr[i] = *(const short8*)(&Bs[(wn + i * 16 + l16) * 32 + quad * 8]);
#pragma unroll
        for (int mi = 0; mi < 4; mi++)
#pragma unroll
            for (int ni = 0; ni < 4; ni++)
                acc[mi][ni] = __builtin_amdgcn_mfma_f32_16x16x32_bf16(
                    af[mi], bfr[ni], acc[mi][ni], 0, 0, 0);
        __syncthreads();   // all reads done before next stage overwrites
    }

    if (MODE == 1) {
        const int sect = SECT_OFF + (n0 >> 10);
        const float* bias = (sect == 0) ? b0 : ((sect == 1) ? b1 : b2);
        unsigned short* dst = (sect == 0) ? o0 : ((sect == 1) ? o1 : o2);
        const float scl = (sect == 0) ? QSCALE : 1.0f;
#pragma unroll
        for (int mi = 0; mi < 4; mi++)
#pragma unroll
            for (int ni = 0; ni < 4; ni++) {
                const int colg = n0 + wn + ni * 16 + l16;
                const int cc = colg & 1023;
                const int h = cc >> 6, d = cc & 63;
                const float bv = bias[cc];
#pragma unroll
                for (int r = 0; r < 4; r++) {
                    const int rowg = m0 + wm + mi * 16 + quad * 4 + r;
                    const int b = rowg >> 11, s = rowg & 2047;
                    float v = (acc[mi][ni][r] + bv) * scl;
                    dst[((size_t)(b * 16 + h) * SEQ + s) * 64 + d] = f2bf(v);
                }
            }
    } else {
#pragma unroll
        for (int mi = 0; mi < 4; mi++)
#pragma unroll
            for (int ni = 0; ni < 4; ni++) {
                const int colg = n0 + wn + ni * 16 + l16;
                const float bv = b0[colg];
#pragma unroll
                for (int r = 0; r < 4; r++) {
                    const int rowg = m0 + wm + mi * 16 + quad * 4 + r;
                    float v = acc[mi][ni][r] + bv;
                    if (MODE == 2) {
                        o0[(size_t)rowg * N + colg] = f2bf(fmaxf(v, 0.f));
                    } else {
                        outf[(size_t)rowg * N + colg] = v + res[(size_t)rowg * N + colg];
                    }
                }
            }
    }
}

// ---------------------------------------------------------------------------
// Flash attention v3. Q (pre-scaled by QSCALE), K: [B,H,S,64] bf16.
// VT: [B,H,64,S] bf16. O: [B,S,1024] bf16.
// Fixed-shift base-2 softmax (no running max / alpha; l reduced once at end).
// Register prefetch of next K/V tile hides global latency under compute.
// Ps writes XOR-swizzled (col ^= 8*quad of writer row) -> conflict-free.
// ---------------------------------------------------------------------------
template <bool CAUSAL>
__global__ __launch_bounds__(256)
void attn3_kernel(const unsigned short* __restrict__ Q,
                  const unsigned short* __restrict__ K,
                  const unsigned short* __restrict__ VT,
                  unsigned short* __restrict__ O)
{
    __shared__ unsigned short Ks[128 * 72];     // [key][d]
    __shared__ unsigned short Vt[64 * 136];     // [d][key]
    __shared__ unsigned short Ps[4][16 * 136];  // per-wave [q][key^swz]
    __shared__ float sumS[4][16];
    const int tid  = threadIdx.x;
    const int lane = tid & 63;
    const int wave = tid >> 6;
    const int quad = lane >> 4;
    const int l16  = lane & 15;
    const int bh = blockIdx.y;
    const int qb = blockIdx.x;
    const int q0 = qb * 64;
    const size_t baseK = (size_t)bh * SEQ * 64;
    const size_t baseV = (size_t)bh * 64 * SEQ;

    short8 aq[2];
    {
        const unsigned short* qp = Q + baseK + (size_t)(q0 + wave * 16 + l16) * 64 + quad * 8;
        aq[0] = *(const short8*)(qp);
        aq[1] = *(const short8*)(qp + 32);
    }
    f32x4 acc[4];   // O^T: row d = mi*16+quad*4+r, col q = l16
#pragma unroll
    for (int i = 0; i < 4; i++) acc[i] = f32x4{0.f, 0.f, 0.f, 0.f};
    float lsum[4] = {0.f, 0.f, 0.f, 0.f};

    const int nkb = CAUSAL ? ((qb >> 1) + 1) : (SEQ / 128);
    const int krow = tid >> 1;          // 0..127
    const int kc   = (tid & 1) * 32;
    const int vrow = tid >> 2;          // 0..63
    const int vc   = (tid & 3) * 32;
    const unsigned short* kg = K  + baseK + (size_t)krow * 64 + kc;
    const unsigned short* vg = VT + baseV + (size_t)vrow * SEQ + vc;

    // prefetch tile 0 into registers
    short8 kr0 = *(const short8*)(kg),      kr1 = *(const short8*)(kg + 8);
    short8 kr2 = *(const short8*)(kg + 16), kr3 = *(const short8*)(kg + 24);
    short8 vr0 = *(const short8*)(vg),      vr1 = *(const short8*)(vg + 8);
    short8 vr2 = *(const short8*)(vg + 16), vr3 = *(const short8*)(vg + 24);

    for (int kb = 0; kb < nkb; kb++) {
        __syncthreads();   // previous iteration's LDS readers done
        *(short8*)&Ks[krow * 72 + kc]      = kr0;
        *(short8*)&Ks[krow * 72 + kc + 8]  = kr1;
        *(short8*)&Ks[krow * 72 + kc + 16] = kr2;
        *(short8*)&Ks[krow * 72 + kc + 24] = kr3;
        *(short8*)&Vt[vrow * 136 + vc]      = vr0;
        *(short8*)&Vt[vrow * 136 + vc + 8]  = vr1;
        *(short8*)&Vt[vrow * 136 + vc + 16] = vr2;
        *(short8*)&Vt[vrow * 136 + vc + 24] = vr3;
        if (kb + 1 < nkb) {   // issue next tile's loads; results consumed next iter
            const unsigned short* kg2 = kg + (size_t)(kb + 1) * 128 * 64;
            const unsigned short* vg2 = vg + (size_t)(kb + 1) * 128;
            kr0 = *(const short8*)(kg2);      kr1 = *(const short8*)(kg2 + 8);
            kr2 = *(const short8*)(kg2 + 16); kr3 = *(const short8*)(kg2 + 24);
            vr0 = *(const short8*)(vg2);      vr1 = *(const short8*)(vg2 + 8);
            vr2 = *(const short8*)(vg2 + 16); vr3 = *(const short8*)(vg2 + 24);
        }
        __syncthreads();   // staging visible

        // S = Q K^T : C-layout row q=quad*4+r, col key=nt*16+l16
        f32x4 scf[8];
#pragma unroll
        for (int nt = 0; nt < 8; nt++) {
            f32x4 z = f32x4{0.f, 0.f, 0.f, 0.f};
#pragma unroll
            for (int c = 0; c < 2; c++) {
                short8 bk = *(const short8*)(&Ks[(nt * 16 + l16) * 72 + c * 32 + quad * 8]);
                z = __builtin_amdgcn_mfma_f32_16x16x32_bf16(aq[c], bk, z, 0, 0, 0);
            }
            scf[nt] = z;
        }
        if (CAUSAL) {
            const int k0 = kb * 128;
            const int qg = q0 + wave * 16 + quad * 4;
#pragma unroll
            for (int nt = 0; nt < 8; nt++) {
                const int kg_ = k0 + nt * 16 + l16;
#pragma unroll
                for (int r = 0; r < 4; r++)
                    if (kg_ > qg + r) scf[nt][r] = -1e9f;
            }
        }
        // P = exp2(s - PSHIFT); accumulate l per-lane; scatter P (swizzled)
#pragma unroll
        for (int nt = 0; nt < 8; nt++)
#pragma unroll
            for (int r = 0; r < 4; r++) {
                float pv = EXP2(scf[nt][r] - PSHIFT);
                lsum[r] += pv;
                Ps[wave][(quad * 4 + r) * 136 + ((nt * 16 + l16) ^ (quad * 8))] = f2bf(pv);
            }
        // O^T += V^T @ P^T : A = Vt rows (b128), B = Ps rows (b128, unswizzle)
        const int pswz = 8 * (quad ^ ((l16 >> 2) & 3));
#pragma unroll
        for (int c = 0; c < 4; c++) {
            short8 bp = *(const short8*)(&Ps[wave][l16 * 136 + c * 32 + pswz]);
#pragma unroll
            for (int mi = 0; mi < 4; mi++) {
                short8 av = *(const short8*)(&Vt[(mi * 16 + l16) * 136 + c * 32 + quad * 8]);
                acc[mi] = __builtin_amdgcn_mfma_f32_16x16x32_bf16(av, bp, acc[mi], 0, 0, 0);
            }
        }
    }
    // one-shot reduction of l over the 16 lanes holding each query row
#pragma unroll
    for (int r = 0; r < 4; r++) {
#pragma unroll
        for (int off = 1; off < 16; off <<= 1)
            lsum[r] += __shfl_xor(lsum[r], off, 64);
    }
    if (l16 == 0) {
#pragma unroll
        for (int r = 0; r < 4; r++) sumS[wave][quad * 4 + r] = lsum[r];
    }
    __syncthreads();
    const float rcpL = 1.f / sumS[wave][l16];
    const int b = bh >> 4, h = bh & 15;
    const int qg = q0 + wave * 16 + l16;
#pragma unroll
    for (int mi = 0; mi < 4; mi++) {
        ushort4 o4;
        o4.x = f2bf(acc[mi][0] * rcpL);
        o4.y = f2bf(acc[mi][1] * rcpL);
        o4.z = f2bf(acc[mi][2] * rcpL);
        o4.w = f2bf(acc[mi][3] * rcpL);
        *(ushort4*)&O[(size_t)(b * SEQ + qg) * 1024 + h * 64 + mi * 16 + quad * 4] = o4;
    }
}

// ---------------------------------------------------------------------------
extern "C" void kernel_launch(void* const* d_in, const int* in_sizes, int n_in,
                              void* d_out, int out_size, void* d_ws, size_t ws_size,
                              hipStream_t stream)
{
    (void)in_sizes; (void)n_in; (void)out_size; (void)ws_size;
    const int B = 2, S = SEQ, D = 1024, DFF = 4096;
    const int M = B * S;  // 4096

    const float* x     = (const float*)d_in[0];
    const float* enc   = (const float*)d_in[1];
    const float* sa_wq = (const float*)d_in[4],  *sa_bq = (const float*)d_in[5];
    const float* sa_wk = (const float*)d_in[6],  *sa_bk = (const float*)d_in[7];
    const float* sa_wv = (const float*)d_in[8],  *sa_bv = (const float*)d_in[9];
    const float* sa_wo = (const float*)d_in[10], *sa_bo = (const float*)d_in[11];
    const float* ca_wq = (const float*)d_in[12], *ca_bq = (const float*)d_in[13];
    const float* ca_wk = (const float*)d_in[14], *ca_bk = (const float*)d_in[15];
    const float* ca_wv = (const float*)d_in[16], *ca_bv = (const float*)d_in[17];
    const float* ca_wo = (const float*)d_in[18], *ca_bo = (const float*)d_in[19];
    const float* ff_w1 = (const float*)d_in[20], *ff_b1 = (const float*)d_in[21];
    const float* ff_w2 = (const float*)d_in[22], *ff_b2 = (const float*)d_in[23];
    const float* n1_g  = (const float*)d_in[24], *n1_b = (const float*)d_in[25];
    const float* n2_g  = (const float*)d_in[26], *n2_b = (const float*)d_in[27];
    const float* n3_g  = (const float*)d_in[28], *n3_b = (const float*)d_in[29];
    float* out = (float*)d_out;

    char* p = (char*)d_ws;
    auto carve = [&](size_t bytes) -> char* {
        char* r = p;
        p += (bytes + 255) & ~(size_t)255;
        return r;
    };
    // 8 D x D weights contiguous: [sa_q, sa_k, sa_v, sa_o, ca_q, ca_k, ca_v, ca_o]
    unsigned short* wt8     = (unsigned short*)carve((size_t)8 * D * D * 2);
    unsigned short* wt_sqkv = wt8;                          // q,k,v contiguous
    unsigned short* wt_sao  = wt8 + (size_t)3 * D * D;
    unsigned short* wt_caq  = wt8 + (size_t)4 * D * D;
    unsigned short* wt_cakv = wt8 + (size_t)5 * D * D;      // k,v contiguous
    unsigned short* wt_cao  = wt8 + (size_t)7 * D * D;
    unsigned short* wt_ff1  = (unsigned short*)carve((size_t)D * DFF * 2);
    unsigned short* wt_ff2  = (unsigned short*)carve((size_t)DFF * D * 2);
    unsigned short* encb    = (unsigned short*)carve((size_t)M * D * 2);
    unsigned short* hb      = (unsigned short*)carve((size_t)M * D * 2);
    unsigned short* qbuf    = (unsigned short*)carve((size_t)M * D * 2);
    unsigned short* kbuf    = (unsigned short*)carve((size_t)M * D * 2);
    unsigned short* vbuf    = (unsigned short*)carve((size_t)M * D * 2);
    unsigned short* vtbuf   = (unsigned short*)carve((size_t)M * D * 2);
    unsigned short* ffh     = (unsigned short*)carve((size_t)M * DFF * 2);
    float* x1 = (float*)carve((size_t)M * D * 4);
    unsigned short* abuf = hb;   // lifetimes disjoint
    float* x2 = out;             // block-2 residual in d_out; block-3 in-place

    dim3 blk(256);
    // weight pre-pass
    wtrans8_kernel<<<dim3(32, 32, 8), blk, 0, stream>>>(
        sa_wq, sa_wk, sa_wv, sa_wo, ca_wq, ca_wk, ca_wv, ca_wo, wt8);
    wtrans_kernel<<<dim3(DFF / 32, D / 32), blk, 0, stream>>>(ff_w1, wt_ff1, D, DFF);
    wtrans_kernel<<<dim3(D / 32, DFF / 32), blk, 0, stream>>>(ff_w2, wt_ff2, DFF, D);
    cvt_kernel<<<dim3(M * D / 1024), blk, 0, stream>>>(enc, encb, M * D);

    // ---- block 1: self-attention ----
    ln_kernel<<<dim3(M), blk, 0, stream>>>(x, n1_g, n1_b, hb);
    gemm_kernel<1, 0><<<dim3(3 * D / 128, M / 128), blk, 0, stream>>>(
        hb, wt_sqkv, sa_bq, sa_bk, sa_bv, nullptr, nullptr, qbuf, kbuf, vbuf, M, 3 * D, D);
    vtrans_kernel<<<dim3(S / 64, B * 16), blk, 0, stream>>>(vbuf, vtbuf);
    attn3_kernel<true><<<dim3(S / 64, B * 16), blk, 0, stream>>>(qbuf, kbuf, vtbuf, abuf);
    gemm_kernel<3, 0><<<dim3(D / 128, M / 128), blk, 0, stream>>>(
        abuf, wt_sao, sa_bo, nullptr, nullptr, x, x1, nullptr, nullptr, nullptr, M, D, D);

    // ---- block 2: cross-attention ----
    ln_kernel<<<dim3(M), blk, 0, stream>>>(x1, n2_g, n2_b, hb);
    gemm_kernel<1, 0><<<dim3(D / 128, M / 128), blk, 0, stream>>>(
        hb, wt_caq, ca_bq, nullptr, nullptr, nullptr, nullptr, qbuf, nullptr, nullptr, M, D, D);
    gemm_kernel<1, 1><<<dim3(2 * D / 128, M / 128), blk, 0, stream>>>(
        encb, wt_cakv, nullptr, ca_bk, ca_bv, nullptr, nullptr, nullptr, kbuf, vbuf, M, 2 * D, D);
    vtrans_kernel<<<dim3(S / 64, B * 16), blk, 0, stream>>>(vbuf, vtbuf);
    attn3_kernel<false><<<dim3(S / 64, B * 16), blk, 0, stream>>>(qbuf, kbuf, vtbuf, abuf);
    gemm_kernel<3, 0><<<dim3(D / 128, M / 128), blk, 0, stream>>>(
        abuf, wt_cao, ca_bo, nullptr, nullptr, x1, x2, nullptr, nullptr, nullptr, M, D, D);

    // ---- block 3: feed-forward ----
    ln_kernel<<<dim3(M), blk, 0, stream>>>(x2, n3_g, n3_b, hb);
    gemm_kernel<2, 0><<<dim3(DFF / 128, M / 128), blk, 0, stream>>>(
        hb, wt_ff1, ff_b1, nullptr, nullptr, nullptr, nullptr, ffh, nullptr, nullptr, M, DFF, D);
    gemm_kernel<3, 0><<<dim3(D / 128, M / 128), blk, 0, stream>>>(
        ffh, wt_ff2, ff_b2, nullptr, nullptr, x2, out, nullptr, nullptr, nullptr, M, D, DFF);
}

// Round 6
// 631.667 us; speedup vs baseline: 1.4295x; 1.0688x over previous
//
#include <hip/hip_runtime.h>

typedef short short8 __attribute__((ext_vector_type(8)));
typedef float f32x4 __attribute__((ext_vector_type(4)));

#define SEQ 2048
#define QSCALE 0.18033688011112042f   // 0.125 * log2(e): softmax done in base 2
#define PSHIFT 20.0f                  // fixed softmax shift (cancels in O = acc/l)
#define EXP2(x) __builtin_amdgcn_exp2f(x)

// async global->LDS, 16B per lane; lds base must be wave-uniform
#define GLDS(g, l) __builtin_amdgcn_global_load_lds( \
    (const __attribute__((address_space(1))) unsigned int*)(g), \
    (__attribute__((address_space(3))) unsigned int*)(l), 16, 0, 0)

__device__ __forceinline__ unsigned short f2bf(float f) {
    unsigned int u = __builtin_bit_cast(unsigned int, f);
    unsigned int r = (u + 0x7fffu + ((u >> 16) & 1u)) >> 16;
    return (unsigned short)r;
}

// ---------------------------------------------------------------------------
// Batched weight transpose + fp32->bf16: 8 D x D weights in one launch.
// ---------------------------------------------------------------------------
__global__ __launch_bounds__(256)
void wtrans8_kernel(const float* w0, const float* w1, const float* w2, const float* w3,
                    const float* w4, const float* w5, const float* w6, const float* w7,
                    unsigned short* __restrict__ outbase)
{
    const float* Ws[8] = {w0, w1, w2, w3, w4, w5, w6, w7};
    const float* __restrict__ W = Ws[blockIdx.z];
    unsigned short* __restrict__ Wt = outbase + (size_t)blockIdx.z * 1024 * 1024;
    __shared__ float t[32][33];
    const int tx = threadIdx.x & 31;
    const int ty = threadIdx.x >> 5;
    const int nb = blockIdx.x * 32;
    const int kb = blockIdx.y * 32;
#pragma unroll
    for (int i = 0; i < 4; i++)
        t[ty + i * 8][tx] = W[(size_t)(kb + ty + i * 8) * 1024 + nb + tx];
    __syncthreads();
#pragma unroll
    for (int i = 0; i < 4; i++)
        Wt[(size_t)(nb + ty + i * 8) * 1024 + kb + tx] = f2bf(t[tx][ty + i * 8]);
}

// single weight transpose (for the two FFN shapes)
__global__ __launch_bounds__(256)
void wtrans_kernel(const float* __restrict__ W, unsigned short* __restrict__ Wt,
                   int Kd, int Nd)
{
    __shared__ float t[32][33];
    const int tx = threadIdx.x & 31;
    const int ty = threadIdx.x >> 5;
    const int nb = blockIdx.x * 32;
    const int kb = blockIdx.y * 32;
#pragma unroll
    for (int i = 0; i < 4; i++)
        t[ty + i * 8][tx] = W[(size_t)(kb + ty + i * 8) * Nd + nb + tx];
    __syncthreads();
#pragma unroll
    for (int i = 0; i < 4; i++)
        Wt[(size_t)(nb + ty + i * 8) * Kd + kb + tx] = f2bf(t[tx][ty + i * 8]);
}

// ---------------------------------------------------------------------------
// Elementwise fp32 -> bf16
// ---------------------------------------------------------------------------
__global__ __launch_bounds__(256)
void cvt_kernel(const float* __restrict__ in, unsigned short* __restrict__ out, int n)
{
    int i = (blockIdx.x * 256 + threadIdx.x) * 4;
    if (i < n) {
        float4 v = *(const float4*)(in + i);
        ushort4 o;
        o.x = f2bf(v.x); o.y = f2bf(v.y); o.z = f2bf(v.z); o.w = f2bf(v.w);
        *(ushort4*)(out + i) = o;
    }
}

// ---------------------------------------------------------------------------
// bf16 transpose within each (b,h): V [BH][S][64] -> VT [BH][64][S]
// ---------------------------------------------------------------------------
__global__ __launch_bounds__(256)
void vtrans_kernel(const unsigned short* __restrict__ V, unsigned short* __restrict__ VT)
{
    __shared__ unsigned short t[64][72];
    const int tid = threadIdx.x;
    const int bh = blockIdx.y;
    const int s0 = blockIdx.x * 64;
    const int r4  = tid >> 2;
    const int c16 = (tid & 3) * 16;
    const unsigned short* src = V + (size_t)bh * SEQ * 64 + (size_t)(s0 + r4) * 64;
    *(short8*)&t[r4][c16]     = *(const short8*)(src + c16);
    *(short8*)&t[r4][c16 + 8] = *(const short8*)(src + c16 + 8);
    __syncthreads();
    short8 a, b;
#pragma unroll
    for (int j = 0; j < 8; j++) { a[j] = t[c16 + j][r4]; b[j] = t[c16 + 8 + j][r4]; }
    unsigned short* dst = VT + (size_t)bh * 64 * SEQ + (size_t)r4 * SEQ + s0 + c16;
    *(short8*)dst = a;
    *(short8*)(dst + 8) = b;
}

// ---------------------------------------------------------------------------
// LayerNorm (torch-faithful: ddof=1, eps added to std). fp32 in -> bf16 out.
// ---------------------------------------------------------------------------
__global__ __launch_bounds__(256)
void ln_kernel(const float* __restrict__ x, const float* __restrict__ g,
               const float* __restrict__ bb, unsigned short* __restrict__ out)
{
    const int D = 1024;
    const int row = blockIdx.x;
    const float* xr = x + (size_t)row * D;
    float v[4];
    float s = 0.f, ss = 0.f;
#pragma unroll
    for (int i = 0; i < 4; i++) {
        v[i] = xr[threadIdx.x + i * 256];
        s += v[i];
        ss += v[i] * v[i];
    }
#pragma unroll
    for (int off = 1; off < 64; off <<= 1) {
        s  += __shfl_xor(s,  off, 64);
        ss += __shfl_xor(ss, off, 64);
    }
    __shared__ float red[8];
    const int wave = threadIdx.x >> 6;
    if ((threadIdx.x & 63) == 0) { red[wave] = s; red[4 + wave] = ss; }
    __syncthreads();
    s  = red[0] + red[1] + red[2] + red[3];
    ss = red[4] + red[5] + red[6] + red[7];
    float mean = s / D;
    float var  = fmaxf((ss - s * mean) / (D - 1), 0.f);
    float inv  = 1.f / (sqrtf(var) + 1e-6f);
#pragma unroll
    for (int i = 0; i < 4; i++) {
        int c = threadIdx.x + i * 256;
        out[(size_t)row * D + c] = f2bf(g[c] * (v[i] - mean) * inv + bb[c]);
    }
}

// ---------------------------------------------------------------------------
// Tiled MFMA GEMM (m97 structure): C[M,N] = A[M,K] @ Wt[N,K]^T + bias
// 128x128 tile, BK=32, unpadded LDS, global_load_lds 16B async staging.
// Used where grid >= 512 blocks (QKV, CA-KV, FFN1).
// ---------------------------------------------------------------------------
template <int MODE, int SECT_OFF>
__global__ __launch_bounds__(256)
void gemm_kernel(const unsigned short* __restrict__ A,
                 const unsigned short* __restrict__ Wt,
                 const float* __restrict__ b0,
                 const float* __restrict__ b1,
                 const float* __restrict__ b2,
                 const float* __restrict__ res,
                 float* __restrict__ outf,
                 unsigned short* __restrict__ o0,
                 unsigned short* __restrict__ o1,
                 unsigned short* __restrict__ o2,
                 int M, int N, int K)
{
    __shared__ unsigned short As[128 * 32];
    __shared__ unsigned short Bs[128 * 32];
    const int tid  = threadIdx.x;
    const int lane = tid & 63;
    const int wv   = tid >> 6;
    const int quad = lane >> 4;
    const int l16  = lane & 15;
    const int m0 = blockIdx.y * 128;
    const int n0 = blockIdx.x * 128;
    const int wm = (wv >> 1) << 6;
    const int wn = (wv & 1) << 6;

    const int srow0 = wv * 32 + (lane >> 2);
    const int srow1 = srow0 + 16;
    const int scol8 = (lane & 3) * 8;
    unsigned short* asw0 = &As[(wv * 2 + 0) * 512];
    unsigned short* asw1 = &As[(wv * 2 + 1) * 512];
    unsigned short* bsw0 = &Bs[(wv * 2 + 0) * 512];
    unsigned short* bsw1 = &Bs[(wv * 2 + 1) * 512];
    const unsigned short* Ag0 = A  + (size_t)(m0 + srow0) * K + scol8;
    const unsigned short* Ag1 = A  + (size_t)(m0 + srow1) * K + scol8;
    const unsigned short* Bg0 = Wt + (size_t)(n0 + srow0) * K + scol8;
    const unsigned short* Bg1 = Wt + (size_t)(n0 + srow1) * K + scol8;

    f32x4 acc[4][4];
#pragma unroll
    for (int i = 0; i < 4; i++)
#pragma unroll
        for (int j = 0; j < 4; j++) acc[i][j] = f32x4{0.f, 0.f, 0.f, 0.f};

    for (int k0 = 0; k0 < K; k0 += 32) {
        GLDS(Ag0 + k0, asw0);
        GLDS(Ag1 + k0, asw1);
        GLDS(Bg0 + k0, bsw0);
        GLDS(Bg1 + k0, bsw1);
        __syncthreads();
        short8 af[4], bfr[4];
#pragma unroll
        for (int i = 0; i < 4; i++)
            af[i] = *(const short8*)(&As[(wm + i * 16 + l16) * 32 + quad * 8]);
#pragma unroll
        for (int i = 0; i < 4; i++)
            bfr[i] = *(const short8*)(&Bs[(wn + i * 16 + l16) * 32 + quad * 8]);
#pragma unroll
        for (int mi = 0; mi < 4; mi++)
#pragma unroll
            for (int ni = 0; ni < 4; ni++)
                acc[mi][ni] = __builtin_amdgcn_mfma_f32_16x16x32_bf16(
                    af[mi], bfr[ni], acc[mi][ni], 0, 0, 0);
        __syncthreads();
    }

    if (MODE == 1) {
        const int sect = SECT_OFF + (n0 >> 10);
        const float* bias = (sect == 0) ? b0 : ((sect == 1) ? b1 : b2);
        unsigned short* dst = (sect == 0) ? o0 : ((sect == 1) ? o1 : o2);
        const float scl = (sect == 0) ? QSCALE : 1.0f;
#pragma unroll
        for (int mi = 0; mi < 4; mi++)
#pragma unroll
            for (int ni = 0; ni < 4; ni++) {
                const int colg = n0 + wn + ni * 16 + l16;
                const int cc = colg & 1023;
                const int h = cc >> 6, d = cc & 63;
                const float bv = bias[cc];
#pragma unroll
                for (int r = 0; r < 4; r++) {
                    const int rowg = m0 + wm + mi * 16 + quad * 4 + r;
                    const int b = rowg >> 11, s = rowg & 2047;
                    float v = (acc[mi][ni][r] + bv) * scl;
                    dst[((size_t)(b * 16 + h) * SEQ + s) * 64 + d] = f2bf(v);
                }
            }
    } else {
#pragma unroll
        for (int mi = 0; mi < 4; mi++)
#pragma unroll
            for (int ni = 0; ni < 4; ni++) {
                const int colg = n0 + wn + ni * 16 + l16;
                const float bv = b0[colg];
#pragma unroll
                for (int r = 0; r < 4; r++) {
                    const int rowg = m0 + wm + mi * 16 + quad * 4 + r;
                    float v = acc[mi][ni][r] + bv;
                    if (MODE == 2) {
                        o0[(size_t)rowg * N + colg] = f2bf(fmaxf(v, 0.f));
                    } else {
                        outf[(size_t)rowg * N + colg] = v + res[(size_t)rowg * N + colg];
                    }
                }
            }
    }
}

// ---------------------------------------------------------------------------
// 64x128-tile GEMM for N=1024 shapes whose 128-tile grid would be 256 blocks
// (1 block/CU -> fully exposed barrier drains). Grid (N/128, M/64) = 512
// blocks = 2 blocks/CU; the co-resident block hides the vmcnt drain.
// Waves: 2x2 layout, each wave 32 rows x 64 cols (2x4 subtiles).
// MODE 1: head-scatter bf16 (sect 0 scaled by QSCALE). MODE 3: +res fp32.
// ---------------------------------------------------------------------------
template <int MODE>
__global__ __launch_bounds__(256)
void gemm64_kernel(const unsigned short* __restrict__ A,
                   const unsigned short* __restrict__ Wt,
                   const float* __restrict__ b0,
                   const float* __restrict__ res,
                   float* __restrict__ outf,
                   unsigned short* __restrict__ o0,
                   int M, int N, int K)
{
    __shared__ unsigned short As[64 * 32];
    __shared__ unsigned short Bs[128 * 32];
    const int tid  = threadIdx.x;
    const int lane = tid & 63;
    const int wv   = tid >> 6;
    const int quad = lane >> 4;
    const int l16  = lane & 15;
    const int m0 = blockIdx.y * 64;
    const int n0 = blockIdx.x * 128;
    const int wm = (wv >> 1) << 5;   // 0 or 32
    const int wn = (wv & 1) << 6;    // 0 or 64

    // A staging: wave w covers rows [w*16, w*16+16): 1 issue/wave
    const int arow  = wv * 16 + (lane >> 2);
    // B staging: wave w covers rows [w*32, w*32+32): 2 issues/wave
    const int brow0 = wv * 32 + (lane >> 2);
    const int brow1 = brow0 + 16;
    const int scol8 = (lane & 3) * 8;
    unsigned short* asw  = &As[wv * 512];
    unsigned short* bsw0 = &Bs[(wv * 2 + 0) * 512];
    unsigned short* bsw1 = &Bs[(wv * 2 + 1) * 512];
    const unsigned short* Ag  = A  + (size_t)(m0 + arow)  * K + scol8;
    const unsigned short* Bg0 = Wt + (size_t)(n0 + brow0) * K + scol8;
    const unsigned short* Bg1 = Wt + (size_t)(n0 + brow1) * K + scol8;

    f32x4 acc[2][4];
#pragma unroll
    for (int i = 0; i < 2; i++)
#pragma unroll
        for (int j = 0; j < 4; j++) acc[i][j] = f32x4{0.f, 0.f, 0.f, 0.f};

    for (int k0 = 0; k0 < K; k0 += 32) {
        GLDS(Ag + k0, asw);
        GLDS(Bg0 + k0, bsw0);
        GLDS(Bg1 + k0, bsw1);
        __syncthreads();
        short8 af[2], bfr[4];
#pragma unroll
        for (int i = 0; i < 2; i++)
            af[i] = *(const short8*)(&As[(wm + i * 16 + l16) * 32 + quad * 8]);
#pragma unroll
        for (int i = 0; i < 4; i++)
            bfr[i] = *(const short8*)(&Bs[(wn + i * 16 + l16) * 32 + quad * 8]);
#pragma unroll
        for (int mi = 0; mi < 2; mi++)
#pragma unroll
            for (int ni = 0; ni < 4; ni++)
                acc[mi][ni] = __builtin_amdgcn_mfma_f32_16x16x32_bf16(
                    af[mi], bfr[ni], acc[mi][ni], 0, 0, 0);
        __syncthreads();
    }

#pragma unroll
    for (int mi = 0; mi < 2; mi++)
#pragma unroll
        for (int ni = 0; ni < 4; ni++) {
            const int colg = n0 + wn + ni * 16 + l16;
            const float bv = b0[colg & 1023];
#pragma unroll
            for (int r = 0; r < 4; r++) {
                const int rowg = m0 + wm + mi * 16 + quad * 4 + r;
                if (MODE == 1) {
                    const int cc = colg & 1023;
                    const int h = cc >> 6, d = cc & 63;
                    const int b = rowg >> 11, s = rowg & 2047;
                    float v = (acc[mi][ni][r] + bv) * QSCALE;
                    o0[((size_t)(b * 16 + h) * SEQ + s) * 64 + d] = f2bf(v);
                } else {
                    float v = acc[mi][ni][r] + bv;
                    outf[(size_t)rowg * N + colg] = v + res[(size_t)rowg * N + colg];
                }
            }
        }
}

// ---------------------------------------------------------------------------
// Flash attention v3. Q (pre-scaled by QSCALE), K: [B,H,S,64] bf16.
// VT: [B,H,64,S] bf16. O: [B,S,1024] bf16.
// Fixed-shift base-2 softmax; register prefetch of next K/V tile;
// Ps writes XOR-swizzled.
// ---------------------------------------------------------------------------
template <bool CAUSAL>
__global__ __launch_bounds__(256)
void attn3_kernel(const unsigned short* __restrict__ Q,
                  const unsigned short* __restrict__ K,
                  const unsigned short* __restrict__ VT,
                  unsigned short* __restrict__ O)
{
    __shared__ unsigned short Ks[128 * 72];
    __shared__ unsigned short Vt[64 * 136];
    __shared__ unsigned short Ps[4][16 * 136];
    __shared__ float sumS[4][16];
    const int tid  = threadIdx.x;
    const int lane = tid & 63;
    const int wave = tid >> 6;
    const int quad = lane >> 4;
    const int l16  = lane & 15;
    const int bh = blockIdx.y;
    const int qb = blockIdx.x;
    const int q0 = qb * 64;
    const size_t baseK = (size_t)bh * SEQ * 64;
    const size_t baseV = (size_t)bh * 64 * SEQ;

    short8 aq[2];
    {
        const unsigned short* qp = Q + baseK + (size_t)(q0 + wave * 16 + l16) * 64 + quad * 8;
        aq[0] = *(const short8*)(qp);
        aq[1] = *(const short8*)(qp + 32);
    }
    f32x4 acc[4];
#pragma unroll
    for (int i = 0; i < 4; i++) acc[i] = f32x4{0.f, 0.f, 0.f, 0.f};
    float lsum[4] = {0.f, 0.f, 0.f, 0.f};

    const int nkb = CAUSAL ? ((qb >> 1) + 1) : (SEQ / 128);
    const int krow = tid >> 1;
    const int kc   = (tid & 1) * 32;
    const int vrow = tid >> 2;
    const int vc   = (tid & 3) * 32;
    const unsigned short* kg = K  + baseK + (size_t)krow * 64 + kc;
    const unsigned short* vg = VT + baseV + (size_t)vrow * SEQ + vc;

    short8 kr0 = *(const short8*)(kg),      kr1 = *(const short8*)(kg + 8);
    short8 kr2 = *(const short8*)(kg + 16), kr3 = *(const short8*)(kg + 24);
    short8 vr0 = *(const short8*)(vg),      vr1 = *(const short8*)(vg + 8);
    short8 vr2 = *(const short8*)(vg + 16), vr3 = *(const short8*)(vg + 24);

    for (int kb = 0; kb < nkb; kb++) {
        __syncthreads();
        *(short8*)&Ks[krow * 72 + kc]      = kr0;
        *(short8*)&Ks[krow * 72 + kc + 8]  = kr1;
        *(short8*)&Ks[krow * 72 + kc + 16] = kr2;
        *(short8*)&Ks[krow * 72 + kc + 24] = kr3;
        *(short8*)&Vt[vrow * 136 + vc]      = vr0;
        *(short8*)&Vt[vrow * 136 + vc + 8]  = vr1;
        *(short8*)&Vt[vrow * 136 + vc + 16] = vr2;
        *(short8*)&Vt[vrow * 136 + vc + 24] = vr3;
        if (kb + 1 < nkb) {
            const unsigned short* kg2 = kg + (size_t)(kb + 1) * 128 * 64;
            const unsigned short* vg2 = vg + (size_t)(kb + 1) * 128;
            kr0 = *(const short8*)(kg2);      kr1 = *(const short8*)(kg2 + 8);
            kr2 = *(const short8*)(kg2 + 16); kr3 = *(const short8*)(kg2 + 24);
            vr0 = *(const short8*)(vg2);      vr1 = *(const short8*)(vg2 + 8);
            vr2 = *(const short8*)(vg2 + 16); vr3 = *(const short8*)(vg2 + 24);
        }
        __syncthreads();

        f32x4 scf[8];
#pragma unroll
        for (int nt = 0; nt < 8; nt++) {
            f32x4 z = f32x4{0.f, 0.f, 0.f, 0.f};
#pragma unroll
            for (int c = 0; c < 2; c++) {
                short8 bk = *(const short8*)(&Ks[(nt * 16 + l16) * 72 + c * 32 + quad * 8]);
                z = __builtin_amdgcn_mfma_f32_16x16x32_bf16(aq[c], bk, z, 0, 0, 0);
            }
            scf[nt] = z;
        }
        if (CAUSAL) {
            const int k0 = kb * 128;
            const int qg = q0 + wave * 16 + quad * 4;
#pragma unroll
            for (int nt = 0; nt < 8; nt++) {
                const int kg_ = k0 + nt * 16 + l16;
#pragma unroll
                for (int r = 0; r < 4; r++)
                    if (kg_ > qg + r) scf[nt][r] = -1e9f;
            }
        }
#pragma unroll
        for (int nt = 0; nt < 8; nt++)
#pragma unroll
            for (int r = 0; r < 4; r++) {
                float pv = EXP2(scf[nt][r] - PSHIFT);
                lsum[r] += pv;
                Ps[wave][(quad * 4 + r) * 136 + ((nt * 16 + l16) ^ (quad * 8))] = f2bf(pv);
            }
        const int pswz = 8 * (quad ^ ((l16 >> 2) & 3));
#pragma unroll
        for (int c = 0; c < 4; c++) {
            short8 bp = *(const short8*)(&Ps[wave][l16 * 136 + c * 32 + pswz]);
#pragma unroll
            for (int mi = 0; mi < 4; mi++) {
                short8 av = *(const short8*)(&Vt[(mi * 16 + l16) * 136 + c * 32 + quad * 8]);
                acc[mi] = __builtin_amdgcn_mfma_f32_16x16x32_bf16(av, bp, acc[mi], 0, 0, 0);
            }
        }
    }
#pragma unroll
    for (int r = 0; r < 4; r++) {
#pragma unroll
        for (int off = 1; off < 16; off <<= 1)
            lsum[r] += __shfl_xor(lsum[r], off, 64);
    }
    if (l16 == 0) {
#pragma unroll
        for (int r = 0; r < 4; r++) sumS[wave][quad * 4 + r] = lsum[r];
    }
    __syncthreads();
    const float rcpL = 1.f / sumS[wave][l16];
    const int b = bh >> 4, h = bh & 15;
    const int qg = q0 + wave * 16 + l16;
#pragma unroll
    for (int mi = 0; mi < 4; mi++) {
        ushort4 o4;
        o4.x = f2bf(acc[mi][0] * rcpL);
        o4.y = f2bf(acc[mi][1] * rcpL);
        o4.z = f2bf(acc[mi][2] * rcpL);
        o4.w = f2bf(acc[mi][3] * rcpL);
        *(ushort4*)&O[(size_t)(b * SEQ + qg) * 1024 + h * 64 + mi * 16 + quad * 4] = o4;
    }
}

// ---------------------------------------------------------------------------
extern "C" void kernel_launch(void* const* d_in, const int* in_sizes, int n_in,
                              void* d_out, int out_size, void* d_ws, size_t ws_size,
                              hipStream_t stream)
{
    (void)in_sizes; (void)n_in; (void)out_size; (void)ws_size;
    const int B = 2, S = SEQ, D = 1024, DFF = 4096;
    const int M = B * S;  // 4096

    const float* x     = (const float*)d_in[0];
    const float* enc   = (const float*)d_in[1];
    const float* sa_wq = (const float*)d_in[4],  *sa_bq = (const float*)d_in[5];
    const float* sa_wk = (const float*)d_in[6],  *sa_bk = (const float*)d_in[7];
    const float* sa_wv = (const float*)d_in[8],  *sa_bv = (const float*)d_in[9];
    const float* sa_wo = (const float*)d_in[10], *sa_bo = (const float*)d_in[11];
    const float* ca_wq = (const float*)d_in[12], *ca_bq = (const float*)d_in[13];
    const float* ca_wk = (const float*)d_in[14], *ca_bk = (const float*)d_in[15];
    const float* ca_wv = (const float*)d_in[16], *ca_bv = (const float*)d_in[17];
    const float* ca_wo = (const float*)d_in[18], *ca_bo = (const float*)d_in[19];
    const float* ff_w1 = (const float*)d_in[20], *ff_b1 = (const float*)d_in[21];
    const float* ff_w2 = (const float*)d_in[22], *ff_b2 = (const float*)d_in[23];
    const float* n1_g  = (const float*)d_in[24], *n1_b = (const float*)d_in[25];
    const float* n2_g  = (const float*)d_in[26], *n2_b = (const float*)d_in[27];
    const float* n3_g  = (const float*)d_in[28], *n3_b = (const float*)d_in[29];
    float* out = (float*)d_out;

    char* p = (char*)d_ws;
    auto carve = [&](size_t bytes) -> char* {
        char* r = p;
        p += (bytes + 255) & ~(size_t)255;
        return r;
    };
    unsigned short* wt8     = (unsigned short*)carve((size_t)8 * D * D * 2);
    unsigned short* wt_sqkv = wt8;
    unsigned short* wt_sao  = wt8 + (size_t)3 * D * D;
    unsigned short* wt_caq  = wt8 + (size_t)4 * D * D;
    unsigned short* wt_cakv = wt8 + (size_t)5 * D * D;
    unsigned short* wt_cao  = wt8 + (size_t)7 * D * D;
    unsigned short* wt_ff1  = (unsigned short*)carve((size_t)D * DFF * 2);
    unsigned short* wt_ff2  = (unsigned short*)carve((size_t)DFF * D * 2);
    unsigned short* encb    = (unsigned short*)carve((size_t)M * D * 2);
    unsigned short* hb      = (unsigned short*)carve((size_t)M * D * 2);
    unsigned short* qbuf    = (unsigned short*)carve((size_t)M * D * 2);
    unsigned short* kbuf    = (unsigned short*)carve((size_t)M * D * 2);
    unsigned short* vbuf    = (unsigned short*)carve((size_t)M * D * 2);
    unsigned short* vtbuf   = (unsigned short*)carve((size_t)M * D * 2);
    unsigned short* ffh     = (unsigned short*)carve((size_t)M * DFF * 2);
    float* x1 = (float*)carve((size_t)M * D * 4);
    unsigned short* abuf = hb;   // lifetimes disjoint
    float* x2 = out;             // block-2 residual in d_out; block-3 in-place

    dim3 blk(256);
    wtrans8_kernel<<<dim3(32, 32, 8), blk, 0, stream>>>(
        sa_wq, sa_wk, sa_wv, sa_wo, ca_wq, ca_wk, ca_wv, ca_wo, wt8);
    wtrans_kernel<<<dim3(DFF / 32, D / 32), blk, 0, stream>>>(ff_w1, wt_ff1, D, DFF);
    wtrans_kernel<<<dim3(D / 32, DFF / 32), blk, 0, stream>>>(ff_w2, wt_ff2, DFF, D);
    cvt_kernel<<<dim3(M * D / 1024), blk, 0, stream>>>(enc, encb, M * D);

    // ---- block 1: self-attention ----
    ln_kernel<<<dim3(M), blk, 0, stream>>>(x, n1_g, n1_b, hb);
    gemm_kernel<1, 0><<<dim3(3 * D / 128, M / 128), blk, 0, stream>>>(
        hb, wt_sqkv, sa_bq, sa_bk, sa_bv, nullptr, nullptr, qbuf, kbuf, vbuf, M, 3 * D, D);
    vtrans_kernel<<<dim3(S / 64, B * 16), blk, 0, stream>>>(vbuf, vtbuf);
    attn3_kernel<true><<<dim3(S / 64, B * 16), blk, 0, stream>>>(qbuf, kbuf, vtbuf, abuf);
    gemm64_kernel<3><<<dim3(D / 128, M / 64), blk, 0, stream>>>(
        abuf, wt_sao, sa_bo, x, x1, nullptr, M, D, D);

    // ---- block 2: cross-attention ----
    ln_kernel<<<dim3(M), blk, 0, stream>>>(x1, n2_g, n2_b, hb);
    gemm64_kernel<1><<<dim3(D / 128, M / 64), blk, 0, stream>>>(
        hb, wt_caq, ca_bq, nullptr, nullptr, qbuf, M, D, D);
    gemm_kernel<1, 1><<<dim3(2 * D / 128, M / 128), blk, 0, stream>>>(
        encb, wt_cakv, nullptr, ca_bk, ca_bv, nullptr, nullptr, nullptr, kbuf, vbuf, M, 2 * D, D);
    vtrans_kernel<<<dim3(S / 64, B * 16), blk, 0, stream>>>(vbuf, vtbuf);
    attn3_kernel<false><<<dim3(S / 64, B * 16), blk, 0, stream>>>(qbuf, kbuf, vtbuf, abuf);
    gemm64_kernel<3><<<dim3(D / 128, M / 64), blk, 0, stream>>>(
        abuf, wt_cao, ca_bo, x1, x2, nullptr, M, D, D);

    // ---- block 3: feed-forward ----
    ln_kernel<<<dim3(M), blk, 0, stream>>>(x2, n3_g, n3_b, hb);
    gemm_kernel<2, 0><<<dim3(DFF / 128, M / 128), blk, 0, stream>>>(
        hb, wt_ff1, ff_b1, nullptr, nullptr, nullptr, nullptr, ffh, nullptr, nullptr, M, DFF, D);
    gemm64_kernel<3><<<dim3(D / 128, M / 64), blk, 0, stream>>>(
        ffh, wt_ff2, ff_b2, x2, out, nullptr, M, D, DFF);
}

// Round 7
// 597.710 us; speedup vs baseline: 1.5107x; 1.0568x over previous
//
#include <hip/hip_runtime.h>

typedef short short8 __attribute__((ext_vector_type(8)));
typedef float f32x4 __attribute__((ext_vector_type(4)));

#define SEQ 2048
#define QSCALE 0.18033688011112042f   // 0.125 * log2(e): softmax done in base 2
#define PSHIFT 20.0f                  // fixed softmax shift (cancels in O = acc/l)
#define EXP2(x) __builtin_amdgcn_exp2f(x)

// async global->LDS, 16B per lane; lds base must be wave-uniform
#define GLDS(g, l) __builtin_amdgcn_global_load_lds( \
    (const __attribute__((address_space(1))) unsigned int*)(g), \
    (__attribute__((address_space(3))) unsigned int*)(l), 16, 0, 0)

__device__ __forceinline__ unsigned short f2bf(float f) {
    unsigned int u = __builtin_bit_cast(unsigned int, f);
    unsigned int r = (u + 0x7fffu + ((u >> 16) & 1u)) >> 16;
    return (unsigned short)r;
}

// ---------------------------------------------------------------------------
// Batched weight transpose + fp32->bf16: 8 D x D weights in one launch.
// ---------------------------------------------------------------------------
__global__ __launch_bounds__(256)
void wtrans8_kernel(const float* w0, const float* w1, const float* w2, const float* w3,
                    const float* w4, const float* w5, const float* w6, const float* w7,
                    unsigned short* __restrict__ outbase)
{
    const float* Ws[8] = {w0, w1, w2, w3, w4, w5, w6, w7};
    const float* __restrict__ W = Ws[blockIdx.z];
    unsigned short* __restrict__ Wt = outbase + (size_t)blockIdx.z * 1024 * 1024;
    __shared__ float t[32][33];
    const int tx = threadIdx.x & 31;
    const int ty = threadIdx.x >> 5;
    const int nb = blockIdx.x * 32;
    const int kb = blockIdx.y * 32;
#pragma unroll
    for (int i = 0; i < 4; i++)
        t[ty + i * 8][tx] = W[(size_t)(kb + ty + i * 8) * 1024 + nb + tx];
    __syncthreads();
#pragma unroll
    for (int i = 0; i < 4; i++)
        Wt[(size_t)(nb + ty + i * 8) * 1024 + kb + tx] = f2bf(t[tx][ty + i * 8]);
}

// single weight transpose (for the two FFN shapes)
__global__ __launch_bounds__(256)
void wtrans_kernel(const float* __restrict__ W, unsigned short* __restrict__ Wt,
                   int Kd, int Nd)
{
    __shared__ float t[32][33];
    const int tx = threadIdx.x & 31;
    const int ty = threadIdx.x >> 5;
    const int nb = blockIdx.x * 32;
    const int kb = blockIdx.y * 32;
#pragma unroll
    for (int i = 0; i < 4; i++)
        t[ty + i * 8][tx] = W[(size_t)(kb + ty + i * 8) * Nd + nb + tx];
    __syncthreads();
#pragma unroll
    for (int i = 0; i < 4; i++)
        Wt[(size_t)(nb + ty + i * 8) * Kd + kb + tx] = f2bf(t[tx][ty + i * 8]);
}

// ---------------------------------------------------------------------------
// Elementwise fp32 -> bf16
// ---------------------------------------------------------------------------
__global__ __launch_bounds__(256)
void cvt_kernel(const float* __restrict__ in, unsigned short* __restrict__ out, int n)
{
    int i = (blockIdx.x * 256 + threadIdx.x) * 4;
    if (i < n) {
        float4 v = *(const float4*)(in + i);
        ushort4 o;
        o.x = f2bf(v.x); o.y = f2bf(v.y); o.z = f2bf(v.z); o.w = f2bf(v.w);
        *(ushort4*)(out + i) = o;
    }
}

// ---------------------------------------------------------------------------
// LayerNorm (torch-faithful: ddof=1, eps added to std). fp32 in -> bf16 out.
// ---------------------------------------------------------------------------
__global__ __launch_bounds__(256)
void ln_kernel(const float* __restrict__ x, const float* __restrict__ g,
               const float* __restrict__ bb, unsigned short* __restrict__ out)
{
    const int D = 1024;
    const int row = blockIdx.x;
    const float* xr = x + (size_t)row * D;
    float v[4];
    float s = 0.f, ss = 0.f;
#pragma unroll
    for (int i = 0; i < 4; i++) {
        v[i] = xr[threadIdx.x + i * 256];
        s += v[i];
        ss += v[i] * v[i];
    }
#pragma unroll
    for (int off = 1; off < 64; off <<= 1) {
        s  += __shfl_xor(s,  off, 64);
        ss += __shfl_xor(ss, off, 64);
    }
    __shared__ float red[8];
    const int wave = threadIdx.x >> 6;
    if ((threadIdx.x & 63) == 0) { red[wave] = s; red[4 + wave] = ss; }
    __syncthreads();
    s  = red[0] + red[1] + red[2] + red[3];
    ss = red[4] + red[5] + red[6] + red[7];
    float mean = s / D;
    float var  = fmaxf((ss - s * mean) / (D - 1), 0.f);
    float inv  = 1.f / (sqrtf(var) + 1e-6f);
#pragma unroll
    for (int i = 0; i < 4; i++) {
        int c = threadIdx.x + i * 256;
        out[(size_t)row * D + c] = f2bf(g[c] * (v[i] - mean) * inv + bb[c]);
    }
}

// ---------------------------------------------------------------------------
// Tiled MFMA GEMM (m97 structure): C[M,N] = A[M,K] @ Wt[N,K]^T + bias
// 128x128 tile, BK=32, unpadded LDS, global_load_lds 16B async staging.
// MODE 1: projection GEMM. Section = n0>>10: 0 -> Q (from A, scaled QSCALE,
//         head layout [B,H,S,64]); 1 -> K (from A2, head layout);
//         2 -> V (from A2, written TRANSPOSED [B,H,64,S] as packed ushort4).
// MODE 2: relu -> bf16 row-major [M,N]    (FFN first GEMM, o0)
// ---------------------------------------------------------------------------
template <int MODE>
__global__ __launch_bounds__(256)
void gemm_kernel(const unsigned short* __restrict__ A,
                 const unsigned short* __restrict__ A2,
                 const unsigned short* __restrict__ Wt,
                 const float* __restrict__ b0,
                 const float* __restrict__ b1,
                 const float* __restrict__ b2,
                 unsigned short* __restrict__ o0,
                 unsigned short* __restrict__ o1,
                 unsigned short* __restrict__ o2,
                 int M, int N, int K)
{
    __shared__ unsigned short As[128 * 32];
    __shared__ unsigned short Bs[128 * 32];
    const int tid  = threadIdx.x;
    const int lane = tid & 63;
    const int wv   = tid >> 6;
    const int quad = lane >> 4;
    const int l16  = lane & 15;
    const int m0 = blockIdx.y * 128;
    const int n0 = blockIdx.x * 128;
    const int wm = (wv >> 1) << 6;
    const int wn = (wv & 1) << 6;
    const int sect = (MODE == 1) ? (n0 >> 10) : 0;
    const unsigned short* Asel = (MODE == 1 && sect != 0) ? A2 : A;

    const int srow0 = wv * 32 + (lane >> 2);
    const int srow1 = srow0 + 16;
    const int scol8 = (lane & 3) * 8;
    unsigned short* asw0 = &As[(wv * 2 + 0) * 512];
    unsigned short* asw1 = &As[(wv * 2 + 1) * 512];
    unsigned short* bsw0 = &Bs[(wv * 2 + 0) * 512];
    unsigned short* bsw1 = &Bs[(wv * 2 + 1) * 512];
    const unsigned short* Ag0 = Asel + (size_t)(m0 + srow0) * K + scol8;
    const unsigned short* Ag1 = Asel + (size_t)(m0 + srow1) * K + scol8;
    const unsigned short* Bg0 = Wt   + (size_t)(n0 + srow0) * K + scol8;
    const unsigned short* Bg1 = Wt   + (size_t)(n0 + srow1) * K + scol8;

    f32x4 acc[4][4];
#pragma unroll
    for (int i = 0; i < 4; i++)
#pragma unroll
        for (int j = 0; j < 4; j++) acc[i][j] = f32x4{0.f, 0.f, 0.f, 0.f};

    for (int k0 = 0; k0 < K; k0 += 32) {
        GLDS(Ag0 + k0, asw0);
        GLDS(Ag1 + k0, asw1);
        GLDS(Bg0 + k0, bsw0);
        GLDS(Bg1 + k0, bsw1);
        __syncthreads();
        short8 af[4], bfr[4];
#pragma unroll
        for (int i = 0; i < 4; i++)
            af[i] = *(const short8*)(&As[(wm + i * 16 + l16) * 32 + quad * 8]);
#pragma unroll
        for (int i = 0; i < 4; i++)
            bfr[i] = *(const short8*)(&Bs[(wn + i * 16 + l16) * 32 + quad * 8]);
#pragma unroll
        for (int mi = 0; mi < 4; mi++)
#pragma unroll
            for (int ni = 0; ni < 4; ni++)
                acc[mi][ni] = __builtin_amdgcn_mfma_f32_16x16x32_bf16(
                    af[mi], bfr[ni], acc[mi][ni], 0, 0, 0);
        __syncthreads();
    }

    if (MODE == 1) {
        const float* bias = (sect == 0) ? b0 : ((sect == 1) ? b1 : b2);
        if (sect == 2) {
            // V: write transposed [B,H,64,S], 4 consecutive s packed per store
#pragma unroll
            for (int mi = 0; mi < 4; mi++)
#pragma unroll
                for (int ni = 0; ni < 4; ni++) {
                    const int cc = (n0 + wn + ni * 16 + l16) & 1023;
                    const int h = cc >> 6, d = cc & 63;
                    const float bv = bias[cc];
                    const int rowg = m0 + wm + mi * 16 + quad * 4;
                    const int b = rowg >> 11, s = rowg & 2047;
                    ushort4 o4;
                    o4.x = f2bf(acc[mi][ni][0] + bv);
                    o4.y = f2bf(acc[mi][ni][1] + bv);
                    o4.z = f2bf(acc[mi][ni][2] + bv);
                    o4.w = f2bf(acc[mi][ni][3] + bv);
                    *(ushort4*)&o2[((size_t)(b * 16 + h) * 64 + d) * SEQ + s] = o4;
                }
        } else {
            unsigned short* dst = (sect == 0) ? o0 : o1;
            const float scl = (sect == 0) ? QSCALE : 1.0f;
#pragma unroll
            for (int mi = 0; mi < 4; mi++)
#pragma unroll
                for (int ni = 0; ni < 4; ni++) {
                    const int cc = (n0 + wn + ni * 16 + l16) & 1023;
                    const int h = cc >> 6, d = cc & 63;
                    const float bv = bias[cc];
#pragma unroll
                    for (int r = 0; r < 4; r++) {
                        const int rowg = m0 + wm + mi * 16 + quad * 4 + r;
                        const int b = rowg >> 11, s = rowg & 2047;
                        float v = (acc[mi][ni][r] + bv) * scl;
                        dst[((size_t)(b * 16 + h) * SEQ + s) * 64 + d] = f2bf(v);
                    }
                }
        }
    } else {
#pragma unroll
        for (int mi = 0; mi < 4; mi++)
#pragma unroll
            for (int ni = 0; ni < 4; ni++) {
                const int colg = n0 + wn + ni * 16 + l16;
                const float bv = b0[colg];
#pragma unroll
                for (int r = 0; r < 4; r++) {
                    const int rowg = m0 + wm + mi * 16 + quad * 4 + r;
                    float v = acc[mi][ni][r] + bv;
                    o0[(size_t)rowg * N + colg] = f2bf(fmaxf(v, 0.f));
                }
            }
    }
}

// ---------------------------------------------------------------------------
// 64x128-tile GEMM (+res fp32) for N=1024 output projections / FFN2:
// grid (8, 64) = 512 blocks = 2 blocks/CU so barrier drains overlap.
// ---------------------------------------------------------------------------
__global__ __launch_bounds__(256)
void gemm64_kernel(const unsigned short* __restrict__ A,
                   const unsigned short* __restrict__ Wt,
                   const float* __restrict__ b0,
                   const float* __restrict__ res,
                   float* __restrict__ outf,
                   int M, int N, int K)
{
    __shared__ unsigned short As[64 * 32];
    __shared__ unsigned short Bs[128 * 32];
    const int tid  = threadIdx.x;
    const int lane = tid & 63;
    const int wv   = tid >> 6;
    const int quad = lane >> 4;
    const int l16  = lane & 15;
    const int m0 = blockIdx.y * 64;
    const int n0 = blockIdx.x * 128;
    const int wm = (wv >> 1) << 5;
    const int wn = (wv & 1) << 6;

    const int arow  = wv * 16 + (lane >> 2);
    const int brow0 = wv * 32 + (lane >> 2);
    const int brow1 = brow0 + 16;
    const int scol8 = (lane & 3) * 8;
    unsigned short* asw  = &As[wv * 512];
    unsigned short* bsw0 = &Bs[(wv * 2 + 0) * 512];
    unsigned short* bsw1 = &Bs[(wv * 2 + 1) * 512];
    const unsigned short* Ag  = A  + (size_t)(m0 + arow)  * K + scol8;
    const unsigned short* Bg0 = Wt + (size_t)(n0 + brow0) * K + scol8;
    const unsigned short* Bg1 = Wt + (size_t)(n0 + brow1) * K + scol8;

    f32x4 acc[2][4];
#pragma unroll
    for (int i = 0; i < 2; i++)
#pragma unroll
        for (int j = 0; j < 4; j++) acc[i][j] = f32x4{0.f, 0.f, 0.f, 0.f};

    for (int k0 = 0; k0 < K; k0 += 32) {
        GLDS(Ag + k0, asw);
        GLDS(Bg0 + k0, bsw0);
        GLDS(Bg1 + k0, bsw1);
        __syncthreads();
        short8 af[2], bfr[4];
#pragma unroll
        for (int i = 0; i < 2; i++)
            af[i] = *(const short8*)(&As[(wm + i * 16 + l16) * 32 + quad * 8]);
#pragma unroll
        for (int i = 0; i < 4; i++)
            bfr[i] = *(const short8*)(&Bs[(wn + i * 16 + l16) * 32 + quad * 8]);
#pragma unroll
        for (int mi = 0; mi < 2; mi++)
#pragma unroll
            for (int ni = 0; ni < 4; ni++)
                acc[mi][ni] = __builtin_amdgcn_mfma_f32_16x16x32_bf16(
                    af[mi], bfr[ni], acc[mi][ni], 0, 0, 0);
        __syncthreads();
    }

#pragma unroll
    for (int mi = 0; mi < 2; mi++)
#pragma unroll
        for (int ni = 0; ni < 4; ni++) {
            const int colg = n0 + wn + ni * 16 + l16;
            const float bv = b0[colg];
#pragma unroll
            for (int r = 0; r < 4; r++) {
                const int rowg = m0 + wm + mi * 16 + quad * 4 + r;
                float v = acc[mi][ni][r] + bv;
                outf[(size_t)rowg * N + colg] = v + res[(size_t)rowg * N + colg];
            }
        }
}

// ---------------------------------------------------------------------------
// Flash attention v4: 128 queries/block (32/wave). Q (pre-scaled), K:
// [B,H,S,64]; VT: [B,H,64,S]; O: [B,S,1024] bf16.
// Fixed-shift base-2 softmax; register prefetch of next K/V tile; Ps
// XOR-swizzled. Causal: blockIdx remapped so co-resident block pairs have
// constant total work (kills the straggler imbalance).
// ---------------------------------------------------------------------------
template <bool CAUSAL>
__global__ __launch_bounds__(256, 2)
void attn4_kernel(const unsigned short* __restrict__ Q,
                  const unsigned short* __restrict__ K,
                  const unsigned short* __restrict__ VT,
                  unsigned short* __restrict__ O)
{
    __shared__ unsigned short Ks[128 * 72];
    __shared__ unsigned short Vt[64 * 136];
    __shared__ unsigned short Ps[4][32 * 136];
    __shared__ float sumS[4][32];
    const int tid  = threadIdx.x;
    const int lane = tid & 63;
    const int wave = tid >> 6;
    const int quad = lane >> 4;
    const int l16  = lane & 15;
    const int bh = blockIdx.y;
    // causal: pair heavy with light so each CU's two blocks sum to 17 tiles
    const int qb = (CAUSAL && (bh & 16)) ? (15 - (int)blockIdx.x) : (int)blockIdx.x;
    const int q0 = qb * 128;
    const size_t baseK = (size_t)bh * SEQ * 64;
    const size_t baseV = (size_t)bh * 64 * SEQ;

    short8 aq[2][2];
#pragma unroll
    for (int qs = 0; qs < 2; qs++) {
        const unsigned short* qp =
            Q + baseK + (size_t)(q0 + wave * 32 + qs * 16 + l16) * 64 + quad * 8;
        aq[qs][0] = *(const short8*)(qp);
        aq[qs][1] = *(const short8*)(qp + 32);
    }
    f32x4 acc[4][2];   // [mi(d)][qs]: O^T row d=mi*16+quad*4+r, col q=l16
#pragma unroll
    for (int i = 0; i < 4; i++)
#pragma unroll
        for (int j = 0; j < 2; j++) acc[i][j] = f32x4{0.f, 0.f, 0.f, 0.f};
    float lsum[2][4] = {{0.f, 0.f, 0.f, 0.f}, {0.f, 0.f, 0.f, 0.f}};

    const int nkb = CAUSAL ? (qb + 1) : (SEQ / 128);
    const int krow = tid >> 1;
    const int kc   = (tid & 1) * 32;
    const int vrow = tid >> 2;
    const int vc   = (tid & 3) * 32;
    const unsigned short* kg = K  + baseK + (size_t)krow * 64 + kc;
    const unsigned short* vg = VT + baseV + (size_t)vrow * SEQ + vc;

    short8 kr0 = *(const short8*)(kg),      kr1 = *(const short8*)(kg + 8);
    short8 kr2 = *(const short8*)(kg + 16), kr3 = *(const short8*)(kg + 24);
    short8 vr0 = *(const short8*)(vg),      vr1 = *(const short8*)(vg + 8);
    short8 vr2 = *(const short8*)(vg + 16), vr3 = *(const short8*)(vg + 24);

    for (int kb = 0; kb < nkb; kb++) {
        __syncthreads();
        *(short8*)&Ks[krow * 72 + kc]      = kr0;
        *(short8*)&Ks[krow * 72 + kc + 8]  = kr1;
        *(short8*)&Ks[krow * 72 + kc + 16] = kr2;
        *(short8*)&Ks[krow * 72 + kc + 24] = kr3;
        *(short8*)&Vt[vrow * 136 + vc]      = vr0;
        *(short8*)&Vt[vrow * 136 + vc + 8]  = vr1;
        *(short8*)&Vt[vrow * 136 + vc + 16] = vr2;
        *(short8*)&Vt[vrow * 136 + vc + 24] = vr3;
        if (kb + 1 < nkb) {
            const unsigned short* kg2 = kg + (size_t)(kb + 1) * 128 * 64;
            const unsigned short* vg2 = vg + (size_t)(kb + 1) * 128;
            kr0 = *(const short8*)(kg2);      kr1 = *(const short8*)(kg2 + 8);
            kr2 = *(const short8*)(kg2 + 16); kr3 = *(const short8*)(kg2 + 24);
            vr0 = *(const short8*)(vg2);      vr1 = *(const short8*)(vg2 + 8);
            vr2 = *(const short8*)(vg2 + 16); vr3 = *(const short8*)(vg2 + 24);
        }
        __syncthreads();

        const bool maskTile = CAUSAL && (kb == nkb - 1);
#pragma unroll
        for (int qs = 0; qs < 2; qs++) {
            f32x4 scf[8];
#pragma unroll
            for (int nt = 0; nt < 8; nt++) {
                f32x4 z = f32x4{0.f, 0.f, 0.f, 0.f};
#pragma unroll
                for (int c = 0; c < 2; c++) {
                    short8 bk = *(const short8*)(&Ks[(nt * 16 + l16) * 72 + c * 32 + quad * 8]);
                    z = __builtin_amdgcn_mfma_f32_16x16x32_bf16(aq[qs][c], bk, z, 0, 0, 0);
                }
                scf[nt] = z;
            }
            if (maskTile) {
                const int qg = q0 + wave * 32 + qs * 16 + quad * 4;
                const int k0 = kb * 128;
#pragma unroll
                for (int nt = 0; nt < 8; nt++) {
                    const int kg_ = k0 + nt * 16 + l16;
#pragma unroll
                    for (int r = 0; r < 4; r++)
                        if (kg_ > qg + r) scf[nt][r] = -1e9f;
                }
            }
#pragma unroll
            for (int nt = 0; nt < 8; nt++)
#pragma unroll
                for (int r = 0; r < 4; r++) {
                    float pv = EXP2(scf[nt][r] - PSHIFT);
                    lsum[qs][r] += pv;
                    Ps[wave][(qs * 16 + quad * 4 + r) * 136 +
                             ((nt * 16 + l16) ^ (quad * 8))] = f2bf(pv);
                }
        }
        // O^T += V^T @ P^T, both operands contiguous b128; Vt reads shared
        const int pswz = 8 * (quad ^ ((l16 >> 2) & 3));
#pragma unroll
        for (int c = 0; c < 4; c++) {
            short8 av[4];
#pragma unroll
            for (int mi = 0; mi < 4; mi++)
                av[mi] = *(const short8*)(&Vt[(mi * 16 + l16) * 136 + c * 32 + quad * 8]);
#pragma unroll
            for (int qs = 0; qs < 2; qs++) {
                short8 bp = *(const short8*)(&Ps[wave][(qs * 16 + l16) * 136 + c * 32 + pswz]);
#pragma unroll
                for (int mi = 0; mi < 4; mi++)
                    acc[mi][qs] = __builtin_amdgcn_mfma_f32_16x16x32_bf16(av[mi], bp, acc[mi][qs], 0, 0, 0);
            }
        }
    }
#pragma unroll
    for (int qs = 0; qs < 2; qs++)
#pragma unroll
        for (int r = 0; r < 4; r++) {
#pragma unroll
            for (int off = 1; off < 16; off <<= 1)
                lsum[qs][r] += __shfl_xor(lsum[qs][r], off, 64);
        }
    if (l16 == 0) {
#pragma unroll
        for (int qs = 0; qs < 2; qs++)
#pragma unroll
            for (int r = 0; r < 4; r++)
                sumS[wave][qs * 16 + quad * 4 + r] = lsum[qs][r];
    }
    __syncthreads();
    const int b = bh >> 4, h = bh & 15;
#pragma unroll
    for (int qs = 0; qs < 2; qs++) {
        const float rcpL = 1.f / sumS[wave][qs * 16 + l16];
        const int qg = q0 + wave * 32 + qs * 16 + l16;
#pragma unroll
        for (int mi = 0; mi < 4; mi++) {
            ushort4 o4;
            o4.x = f2bf(acc[mi][qs][0] * rcpL);
            o4.y = f2bf(acc[mi][qs][1] * rcpL);
            o4.z = f2bf(acc[mi][qs][2] * rcpL);
            o4.w = f2bf(acc[mi][qs][3] * rcpL);
            *(ushort4*)&O[(size_t)(b * SEQ + qg) * 1024 + h * 64 + mi * 16 + quad * 4] = o4;
        }
    }
}

// ---------------------------------------------------------------------------
extern "C" void kernel_launch(void* const* d_in, const int* in_sizes, int n_in,
                              void* d_out, int out_size, void* d_ws, size_t ws_size,
                              hipStream_t stream)
{
    (void)in_sizes; (void)n_in; (void)out_size; (void)ws_size;
    const int B = 2, S = SEQ, D = 1024, DFF = 4096;
    const int M = B * S;  // 4096

    const float* x     = (const float*)d_in[0];
    const float* enc   = (const float*)d_in[1];
    const float* sa_wq = (const float*)d_in[4],  *sa_bq = (const float*)d_in[5];
    const float* sa_wk = (const float*)d_in[6],  *sa_bk = (const float*)d_in[7];
    const float* sa_wv = (const float*)d_in[8],  *sa_bv = (const float*)d_in[9];
    const float* sa_wo = (const float*)d_in[10], *sa_bo = (const float*)d_in[11];
    const float* ca_wq = (const float*)d_in[12], *ca_bq = (const float*)d_in[13];
    const float* ca_wk = (const float*)d_in[14], *ca_bk = (const float*)d_in[15];
    const float* ca_wv = (const float*)d_in[16], *ca_bv = (const float*)d_in[17];
    const float* ca_wo = (const float*)d_in[18], *ca_bo = (const float*)d_in[19];
    const float* ff_w1 = (const float*)d_in[20], *ff_b1 = (const float*)d_in[21];
    const float* ff_w2 = (const float*)d_in[22], *ff_b2 = (const float*)d_in[23];
    const float* n1_g  = (const float*)d_in[24], *n1_b = (const float*)d_in[25];
    const float* n2_g  = (const float*)d_in[26], *n2_b = (const float*)d_in[27];
    const float* n3_g  = (const float*)d_in[28], *n3_b = (const float*)d_in[29];
    float* out = (float*)d_out;

    char* p = (char*)d_ws;
    auto carve = [&](size_t bytes) -> char* {
        char* r = p;
        p += (bytes + 255) & ~(size_t)255;
        return r;
    };
    unsigned short* wt8     = (unsigned short*)carve((size_t)8 * D * D * 2);
    unsigned short* wt_sqkv = wt8;                       // saq, sak, sav contiguous
    unsigned short* wt_sao  = wt8 + (size_t)3 * D * D;
    unsigned short* wt_cqkv = wt8 + (size_t)4 * D * D;   // caq, cak, cav contiguous
    unsigned short* wt_cao  = wt8 + (size_t)7 * D * D;
    unsigned short* wt_ff1  = (unsigned short*)carve((size_t)D * DFF * 2);
    unsigned short* wt_ff2  = (unsigned short*)carve((size_t)DFF * D * 2);
    unsigned short* encb    = (unsigned short*)carve((size_t)M * D * 2);
    unsigned short* hb      = (unsigned short*)carve((size_t)M * D * 2);
    unsigned short* qbuf    = (unsigned short*)carve((size_t)M * D * 2);
    unsigned short* kbuf    = (unsigned short*)carve((size_t)M * D * 2);
    unsigned short* vtbuf   = (unsigned short*)carve((size_t)M * D * 2);
    unsigned short* ffh     = (unsigned short*)carve((size_t)M * DFF * 2);
    float* x1 = (float*)carve((size_t)M * D * 4);
    unsigned short* abuf = hb;   // lifetimes disjoint
    float* x2 = out;             // block-2 residual in d_out; block-3 in-place

    dim3 blk(256);
    wtrans8_kernel<<<dim3(32, 32, 8), blk, 0, stream>>>(
        sa_wq, sa_wk, sa_wv, sa_wo, ca_wq, ca_wk, ca_wv, ca_wo, wt8);
    wtrans_kernel<<<dim3(DFF / 32, D / 32), blk, 0, stream>>>(ff_w1, wt_ff1, D, DFF);
    wtrans_kernel<<<dim3(D / 32, DFF / 32), blk, 0, stream>>>(ff_w2, wt_ff2, DFF, D);
    cvt_kernel<<<dim3(M * D / 1024), blk, 0, stream>>>(enc, encb, M * D);

    // ---- block 1: self-attention ----
    ln_kernel<<<dim3(M), blk, 0, stream>>>(x, n1_g, n1_b, hb);
    gemm_kernel<1><<<dim3(3 * D / 128, M / 128), blk, 0, stream>>>(
        hb, hb, wt_sqkv, sa_bq, sa_bk, sa_bv, qbuf, kbuf, vtbuf, M, 3 * D, D);
    attn4_kernel<true><<<dim3(S / 128, B * 16), blk, 0, stream>>>(qbuf, kbuf, vtbuf, abuf);
    gemm64_kernel<<<dim3(D / 128, M / 64), blk, 0, stream>>>(
        abuf, wt_sao, sa_bo, x, x1, M, D, D);

    // ---- block 2: cross-attention (Q from hb, K/V from encoder) ----
    ln_kernel<<<dim3(M), blk, 0, stream>>>(x1, n2_g, n2_b, hb);
    gemm_kernel<1><<<dim3(3 * D / 128, M / 128), blk, 0, stream>>>(
        hb, encb, wt_cqkv, ca_bq, ca_bk, ca_bv, qbuf, kbuf, vtbuf, M, 3 * D, D);
    attn4_kernel<false><<<dim3(S / 128, B * 16), blk, 0, stream>>>(qbuf, kbuf, vtbuf, abuf);
    gemm64_kernel<<<dim3(D / 128, M / 64), blk, 0, stream>>>(
        abuf, wt_cao, ca_bo, x1, x2, M, D, D);

    // ---- block 3: feed-forward ----
    ln_kernel<<<dim3(M), blk, 0, stream>>>(x2, n3_g, n3_b, hb);
    gemm_kernel<2><<<dim3(DFF / 128, M / 128), blk, 0, stream>>>(
        hb, hb, wt_ff1, ff_b1, nullptr, nullptr, ffh, nullptr, nullptr, M, DFF, D);
    gemm64_kernel<<<dim3(D / 128, M / 64), blk, 0, stream>>>(
        ffh, wt_ff2, ff_b2, x2, out, M, D, DFF);
}